// Round 9
// baseline (2415.833 us; speedup 1.0000x reference)
//
#include <hip/hip_runtime.h>
#include <stdint.h>

#define B_ 4
#define N_ 5000
#define T_ 12
#define FH_ 12
#define H_ 128
#define BN_ 20000
#define E_ 320000
#define TOTE_ (E_ + BN_)
#define EVCAP_ (TOTE_ + BN_)   // room for even-alignment pads

typedef __attribute__((ext_vector_type(8))) short s8v;
typedef __attribute__((ext_vector_type(4))) float f32x4;

__device__ __forceinline__ float fast_tanh(float x) {
  float e = __expf(2.f * x);
  return 1.f - 2.f * __builtin_amdgcn_rcpf(e + 1.f);
}
__device__ __forceinline__ float fast_sigmoid(float x) {
  return __builtin_amdgcn_rcpf(1.f + __expf(-x));
}
__device__ __forceinline__ unsigned short f2bf(float f) {  // RNE
  unsigned u = __float_as_uint(f);
  u = (u + 0x7fffu + ((u >> 16) & 1u)) >> 16;
  return (unsigned short)u;
}
__device__ __forceinline__ float bf2f(unsigned short u) {
  return __uint_as_float(((unsigned)u) << 16);
}
__device__ __forceinline__ unsigned pack2(float lo, float hi) {
  return ((unsigned)f2bf(hi) << 16) | f2bf(lo);
}

__global__ void k_sentinel(float* out) { out[0] = 1e30f; }

__global__ void k_init_cnt(int* cnt) {
  int i = blockIdx.x * 256 + threadIdx.x;
  if (i < BN_) cnt[i] = 1;  // self-loop
}
__global__ void k_count(const int* __restrict__ dst, int* cnt) {
  int e = blockIdx.x * 256 + threadIdx.x;
  if (e < E_) atomicAdd(&cnt[dst[e]], 1);
}
// exclusive scan of cnt -> rp (row starts EVEN-aligned), dinv=rsqrt(cnt); zero cnt
__global__ void k_scan(int* cnt, int* rp, float* dinv) {
  __shared__ int sh[1024];
  int tid = threadIdx.x;
  const int per = (BN_ + 1023) / 1024;
  int start = tid * per;
  int end = start + per; if (end > BN_) end = BN_;
  int s = 0;
  for (int i = start; i < end; i++) {
    int c = cnt[i];
    dinv[i] = rsqrtf((float)c);
    s += (c + 1) & ~1;  // padded length
  }
  sh[tid] = s;
  __syncthreads();
  for (int off = 1; off < 1024; off <<= 1) {
    int v = (tid >= off) ? sh[tid - off] : 0;
    __syncthreads();
    sh[tid] += v;
    __syncthreads();
  }
  int run = (tid > 0) ? sh[tid - 1] : 0;
  for (int i = start; i < end; i++) {
    int c = cnt[i];
    rp[i] = run;
    run += (c + 1) & ~1;
    cnt[i] = 0;
  }
  if (tid == 1023) rp[BN_] = sh[1023];
}
// ev[pos] = {src*128, bits(dinv[s]*dinv[d])}; pad slots stay zero (memset)
__global__ void k_fill(const int* __restrict__ src, const int* __restrict__ dst,
                       const int* __restrict__ rp, int* cnt, int2* ev,
                       const float* __restrict__ dinv) {
  int e = blockIdx.x * 256 + threadIdx.x;
  if (e >= TOTE_) return;
  int s, d;
  if (e < E_) { s = src[e]; d = dst[e]; }
  else { s = d = e - E_; }
  int pos = rp[d] + atomicAdd(&cnt[d], 1);
  int2 p; p.x = s * 128; p.y = __float_as_int(dinv[s] * dinv[d]);
  ev[pos] = p;
}

// ---- degree sort (per batch, DESCENDING: heavy tiles dispatched first) ----
__global__ void k_hist(const int* __restrict__ rp, int* hist) {
  int i = blockIdx.x * 256 + threadIdx.x;
  if (i < BN_) {
    int d = (rp[i + 1] - rp[i]) >> 1; d = d > 63 ? 63 : d;
    atomicAdd(&hist[(i / N_) * 64 + (63 - d)], 1);
  }
}
__global__ void k_binscan(int* hist) {  // 256 bins -> exclusive base (in place)
  __shared__ int sh[256];
  int t = threadIdx.x;
  int val = hist[t];
  sh[t] = val;
  __syncthreads();
  for (int o = 1; o < 256; o <<= 1) {
    int v = (t >= o) ? sh[t - o] : 0;
    __syncthreads();
    sh[t] += v;
    __syncthreads();
  }
  hist[t] = sh[t] - val;  // exclusive; becomes running counter
}
__global__ void k_scatter(const int* __restrict__ rp, int* hist, int* ord) {
  int i = blockIdx.x * 256 + threadIdx.x;
  if (i < BN_) {
    int d = (rp[i + 1] - rp[i]) >> 1; d = d > 63 ? 63 : d;
    int pos = atomicAdd(&hist[(i / N_) * 64 + (63 - d)], 1);
    ord[pos] = i;
  }
}

// MFMA B-frag pack
__device__ __forceinline__ void prep_one(const float* __restrict__ src,
                                         unsigned short* __restrict__ dst,
                                         int K, int Nn, int transposed, int idx) {
  int j = idx & 7, l = (idx >> 3) & 63, rest = idx >> 9;
  int NT = Nn >> 4;
  int nt = rest % NT, kc = rest / NT;
  int k = kc * 32 + ((l >> 4) << 3) + j;
  int n = nt * 16 + (l & 15);
  float v = transposed ? src[n * K + k] : src[k * Nn + n];
  dst[idx] = f2bf(v);
}
__global__ void k_prep_all(const float* w2, const float* w3, const float* a1,
                           const float* o1, const float* o2, const float* wih,
                           unsigned short* w2f, unsigned short* w3f, unsigned short* a1f,
                           unsigned short* o1f, unsigned short* o2f, unsigned short* wihf) {
  int idx = blockIdx.x * 256 + threadIdx.x;
  if (idx < 8192) { prep_one(w2, w2f, 64, 128, 0, idx); return; }
  idx -= 8192;
  if (idx < 16384) { prep_one(w3, w3f, 128, 128, 0, idx); return; }
  idx -= 16384;
  if (idx < 16384) { prep_one(a1, a1f, 128, 128, 0, idx); return; }
  idx -= 16384;
  if (idx < 16384) { prep_one(o1, o1f, 128, 128, 0, idx); return; }
  idx -= 16384;
  if (idx < 16384) { prep_one(o2, o2f, 128, 128, 0, idx); return; }
  idx -= 16384;
  if (idx < 49152) prep_one(wih, wihf, 128, 384, 1, idx);
}

// all-T layer1
__global__ void k_spl1T(const int* __restrict__ rp, const int2* __restrict__ ev,
                        const float* __restrict__ x,
                        const float* __restrict__ w1, const float* __restrict__ b1,
                        unsigned short* __restrict__ h1) {
  int wid = (blockIdx.x * 256 + threadIdx.x) >> 6;
  int lane = threadIdx.x & 63;
  if (wid >= BN_) return;
  int beg = rp[wid], end = rp[wid + 1];
  float a[12];
#pragma unroll
  for (int t = 0; t < 12; t++) a[t] = 0.f;
  for (int e = beg + lane; e < end; e += 64) {
    int2 p = ev[e];
    const float4* xp = (const float4*)(x + (size_t)(p.x >> 7) * 12);
    float v = __int_as_float(p.y);
    float4 x0 = xp[0], x1 = xp[1], x2 = xp[2];
    a[0] = fmaf(v, x0.x, a[0]);  a[1] = fmaf(v, x0.y, a[1]);
    a[2] = fmaf(v, x0.z, a[2]);  a[3] = fmaf(v, x0.w, a[3]);
    a[4] = fmaf(v, x1.x, a[4]);  a[5] = fmaf(v, x1.y, a[5]);
    a[6] = fmaf(v, x1.z, a[6]);  a[7] = fmaf(v, x1.w, a[7]);
    a[8] = fmaf(v, x2.x, a[8]);  a[9] = fmaf(v, x2.y, a[9]);
    a[10] = fmaf(v, x2.z, a[10]); a[11] = fmaf(v, x2.w, a[11]);
  }
#pragma unroll
  for (int t = 0; t < 12; t++)
#pragma unroll
    for (int m = 1; m < 64; m <<= 1) a[t] += __shfl_xor(a[t], m);
  float wv = w1[lane], bv = b1[lane];
#pragma unroll
  for (int t = 0; t < 12; t++) {
    float v = fmaf(a[t], wv, bv);
    __builtin_nontemporal_store(f2bf(fmaxf(v, 0.f)),
                                &h1[((size_t)t * BN_ + wid) * 64 + lane]);
  }
}

// pair-processed 4-way edge-split gather with software-pipelined descriptor prefetch
template<int KIN>
__device__ __forceinline__ void gather_tile(
    const int* __restrict__ rp, const int2* __restrict__ ev,
    const unsigned short* __restrict__ in, unsigned short (*agg)[KIN + 8],
    const int* __restrict__ ordt, int w, int l, int nvalid) {
  const int h = l >> 4, c = l & 15;
  constexpr int CW = KIN / 16;
  const unsigned short* inc = in + c * CW;
  int st[4], len[4];
  float a[4][CW];
  int mx = 0;
  const int4* evp = (const int4*)ev;    // 2 edges per load (16B aligned)
#pragma unroll
  for (int r = 0; r < 4; r++) {
    int lr = w * 4 + r;
    bool ok = lr < nvalid;
    int row = ok ? ordt[lr] : 0;
    int b0 = ok ? rp[row] : 0;
    int e0 = ok ? rp[row + 1] : 0;
    int np = (e0 - b0) >> 1;            // pairs (rows even-aligned)
    int p0 = (np * h) >> 2, p1 = (np * (h + 1)) >> 2;
    st[r] = (b0 >> 1) + p0;
    len[r] = p1 - p0;
    mx = len[r] > mx ? len[r] : mx;
#pragma unroll
    for (int q = 0; q < CW; q++) a[r][q] = 0.f;
  }
  int4 q[4];
#pragma unroll
  for (int r = 0; r < 4; r++) q[r] = evp[st[r]];   // prefetch pair 0 (addr always valid)
  for (int i = 0; i < mx; i++) {
    int4 qn[4];
#pragma unroll
    for (int r = 0; r < 4; r++) {                  // prefetch pair i+1 (off critical path)
      int nx = (i + 1 < len[r]) ? (st[r] + i + 1) : st[r];
      qn[r] = evp[nx];
    }
#pragma unroll
    for (int r = 0; r < 4; r++) {
      if (i < len[r]) {
        float v0 = __int_as_float(q[r].y), v1 = __int_as_float(q[r].w);
        if (KIN == 128) {
          uint4 pA = *(const uint4*)(inc + q[r].x);
          uint4 pB = *(const uint4*)(inc + q[r].z);
          a[r][0] = fmaf(v0, bf2f((unsigned short)(pA.x & 0xffffu)), a[r][0]);
          a[r][1] = fmaf(v0, bf2f((unsigned short)(pA.x >> 16)), a[r][1]);
          a[r][2] = fmaf(v0, bf2f((unsigned short)(pA.y & 0xffffu)), a[r][2]);
          a[r][3] = fmaf(v0, bf2f((unsigned short)(pA.y >> 16)), a[r][3]);
          a[r][4] = fmaf(v0, bf2f((unsigned short)(pA.z & 0xffffu)), a[r][4]);
          a[r][5] = fmaf(v0, bf2f((unsigned short)(pA.z >> 16)), a[r][5]);
          a[r][6] = fmaf(v0, bf2f((unsigned short)(pA.w & 0xffffu)), a[r][6]);
          a[r][7] = fmaf(v0, bf2f((unsigned short)(pA.w >> 16)), a[r][7]);
          a[r][0] = fmaf(v1, bf2f((unsigned short)(pB.x & 0xffffu)), a[r][0]);
          a[r][1] = fmaf(v1, bf2f((unsigned short)(pB.x >> 16)), a[r][1]);
          a[r][2] = fmaf(v1, bf2f((unsigned short)(pB.y & 0xffffu)), a[r][2]);
          a[r][3] = fmaf(v1, bf2f((unsigned short)(pB.y >> 16)), a[r][3]);
          a[r][4] = fmaf(v1, bf2f((unsigned short)(pB.z & 0xffffu)), a[r][4]);
          a[r][5] = fmaf(v1, bf2f((unsigned short)(pB.z >> 16)), a[r][5]);
          a[r][6] = fmaf(v1, bf2f((unsigned short)(pB.w & 0xffffu)), a[r][6]);
          a[r][7] = fmaf(v1, bf2f((unsigned short)(pB.w >> 16)), a[r][7]);
        } else {
          uint2 pA = *(const uint2*)(inc + (q[r].x >> 1));
          uint2 pB = *(const uint2*)(inc + (q[r].z >> 1));
          a[r][0] = fmaf(v0, bf2f((unsigned short)(pA.x & 0xffffu)), a[r][0]);
          a[r][1] = fmaf(v0, bf2f((unsigned short)(pA.x >> 16)), a[r][1]);
          a[r][2] = fmaf(v0, bf2f((unsigned short)(pA.y & 0xffffu)), a[r][2]);
          a[r][3] = fmaf(v0, bf2f((unsigned short)(pA.y >> 16)), a[r][3]);
          a[r][0] = fmaf(v1, bf2f((unsigned short)(pB.x & 0xffffu)), a[r][0]);
          a[r][1] = fmaf(v1, bf2f((unsigned short)(pB.x >> 16)), a[r][1]);
          a[r][2] = fmaf(v1, bf2f((unsigned short)(pB.y & 0xffffu)), a[r][2]);
          a[r][3] = fmaf(v1, bf2f((unsigned short)(pB.y >> 16)), a[r][3]);
        }
      }
    }
#pragma unroll
    for (int r = 0; r < 4; r++) q[r] = qn[r];
  }
#pragma unroll
  for (int r = 0; r < 4; r++) {
#pragma unroll
    for (int q2 = 0; q2 < CW; q2++) {
      a[r][q2] += __shfl_xor(a[r][q2], 16);
      a[r][q2] += __shfl_xor(a[r][q2], 32);
    }
    if (h == 0) {
      if (KIN == 128) {
        uint4 o;
        o.x = pack2(a[r][0], a[r][1]); o.y = pack2(a[r][2], a[r][3]);
        o.z = pack2(a[r][4], a[r][5]); o.w = pack2(a[r][6], a[r][7]);
        *(uint4*)&agg[w * 4 + r][c * 8] = o;
      } else {
        uint2 o;
        o.x = pack2(a[r][0], a[r][1]); o.y = pack2(a[r][2], a[r][3]);
        *(uint2*)&agg[w * 4 + r][c * 4] = o;
      }
    }
  }
}

template<int KIN>
__device__ __forceinline__ void mfma_tile(
    const unsigned short (*agg)[KIN + 8], const unsigned short* __restrict__ Wf,
    int w, int l, f32x4 acc[2]) {
  constexpr int KC = KIN / 32;
  const int hi = l >> 4, lo16 = l & 15;
  acc[0] = (f32x4){0.f, 0.f, 0.f, 0.f};
  acc[1] = (f32x4){0.f, 0.f, 0.f, 0.f};
#pragma unroll
  for (int kc = 0; kc < KC; kc++) {
    s8v av = *(const s8v*)&agg[lo16][kc * 32 + hi * 8];
#pragma unroll
    for (int q = 0; q < 2; q++) {
      s8v bv = *(const s8v*)(Wf + (((size_t)(kc * 8 + 2 * w + q)) << 9) + (l << 3));
      acc[q] = __builtin_amdgcn_mfma_f32_16x16x32_bf16(av, bv, acc[q], 0, 0, 0);
    }
  }
}

// spatial fused SpMM+GEMM (relu), batched over t = blockIdx.y; streaming nt stores
template<int KIN>
__global__ __launch_bounds__(256) void k_fusedT(
    const int* __restrict__ rp, const int2* __restrict__ ev,
    const int* __restrict__ ord,
    const unsigned short* __restrict__ inb, const unsigned short* __restrict__ Wf,
    const float* __restrict__ bias, unsigned short* __restrict__ outb) {
  __shared__ unsigned short agg[16][KIN + 8];
  const int tid = threadIdx.x, l = tid & 63, w = tid >> 6;
  const int t = blockIdx.y;
  const unsigned short* in = inb + (size_t)t * BN_ * KIN;
  unsigned short* out = outb + (size_t)t * BN_ * 128;
  const int bid = blockIdx.x;
  const int xcd = bid & 7, slot = bid >> 3;
  const int bb = xcd >> 1;
  const int within = slot * 2 + (xcd & 1);
  const int wr0 = within * 16;
  int nv = N_ - wr0; nv = nv > 16 ? 16 : nv;
  if (nv <= 0) return;
  const int* ordt = ord + bb * N_ + wr0;
  gather_tile<KIN>(rp, ev, in, agg, ordt, w, l, nv);
  __syncthreads();
  f32x4 acc[2];
  mfma_tile<KIN>(agg, Wf, w, l, acc);
  const int hi = l >> 4, lo16 = l & 15;
#pragma unroll
  for (int q = 0; q < 2; q++) {
    int col = (2 * w + q) * 16 + lo16;
    float bi = bias[col];
#pragma unroll
    for (int reg = 0; reg < 4; reg++) {
      int lr = hi * 4 + reg;
      if (lr < nv) {
        int grow = ordt[lr];
        __builtin_nontemporal_store(f2bf(fmaxf(acc[q][reg] + bi, 0.f)),
                                    &out[(size_t)grow * 128 + col]);
      }
    }
  }
}

// ODE fused SpMM+GEMM+epilogue (KIN=128), modes as before (normal stores: L2 reuse)
__global__ __launch_bounds__(256) void k_fused(
    const int* __restrict__ rp, const int2* __restrict__ ev,
    const int* __restrict__ ord,
    const unsigned short* __restrict__ in,
    const unsigned short* __restrict__ Wf, const float* __restrict__ bias,
    int mode, float c1, float c2,
    unsigned short* __restrict__ outb,
    const unsigned short* __restrict__ hbfin, unsigned short* __restrict__ rkb,
    float* __restrict__ h, unsigned short* __restrict__ ubfout,
    const float* __restrict__ ow, const float* __restrict__ ob,
    float* __restrict__ outp, int step) {
  __shared__ unsigned short agg[16][136];
  __shared__ float ppart[4][16];
  const int tid = threadIdx.x, l = tid & 63, w = tid >> 6;
  const int bid = blockIdx.x;
  const int xcd = bid & 7, slot = bid >> 3;
  const int bb = xcd >> 1;
  const int within = slot * 2 + (xcd & 1);
  const int wr0 = within * 16;
  int nv = N_ - wr0; nv = nv > 16 ? 16 : (nv < 0 ? 0 : nv);
  if (nv <= 0) return;
  const int* ordt = ord + bb * N_ + wr0;
  gather_tile<128>(rp, ev, in, agg, ordt, w, l, nv);
  __syncthreads();
  f32x4 acc[2];
  mfma_tile<128>(agg, Wf, w, l, acc);
  const int hi = l >> 4, lo16 = l & 15;
  float p[4] = {0.f, 0.f, 0.f, 0.f};
#pragma unroll
  for (int q = 0; q < 2; q++) {
    int col = (2 * w + q) * 16 + lo16;
    float bi = bias[col];
    float owv = (mode == 3) ? ow[col] : 0.f;
#pragma unroll
    for (int reg = 0; reg < 4; reg++) {
      int lr = hi * 4 + reg;
      if (lr >= nv) continue;
      int grow = ordt[lr];
      size_t oi = (size_t)grow * 128 + col;
      float v = fast_tanh(acc[q][reg] + bi);
      if (mode == 0) {
        outb[oi] = f2bf(v);
      } else if (mode == 1) {
        rkb[oi] = f2bf(v);
        ubfout[oi] = f2bf(fmaf(c1, v, bf2f(hbfin[oi])));
      } else if (mode == 2) {
        rkb[oi] = f2bf(bf2f(rkb[oi]) + 2.f * v);
        ubfout[oi] = f2bf(fmaf(c1, v, bf2f(hbfin[oi])));
      } else {
        float nh = fmaf(c2, bf2f(rkb[oi]) + v, h[oi]);
        h[oi] = nh;
        ubfout[oi] = f2bf(nh);
        p[reg] = fmaf(nh, owv, p[reg]);
      }
    }
  }
  if (mode == 3) {
#pragma unroll
    for (int m = 1; m <= 8; m <<= 1)
#pragma unroll
      for (int reg = 0; reg < 4; reg++) p[reg] += __shfl_xor(p[reg], m);
    if (lo16 == 0)
#pragma unroll
      for (int reg = 0; reg < 4; reg++) ppart[w][hi * 4 + reg] = p[reg];
    __syncthreads();
    if (tid < 16 && tid < nv) {
      int grow = ordt[tid];
      outp[(size_t)grow * FH_ + step] =
          ppart[0][tid] + ppart[1][tid] + ppart[2][tid] + ppart[3][tid] + ob[0];
    }
  }
}

// attention scores
__global__ __launch_bounds__(256) void k_att(
    const unsigned short* __restrict__ A, const unsigned short* __restrict__ Wf,
    const float* __restrict__ bias, int nrows,
    const float* __restrict__ w2v, const float* __restrict__ b2,
    float* __restrict__ scores) {
  const int tid = threadIdx.x;
  const int l = tid & 63;
  const int w = tid >> 6;
  const int m0 = blockIdx.x * 64 + w * 16;

  f32x4 acc[8];
#pragma unroll
  for (int nt = 0; nt < 8; nt++) acc[nt] = (f32x4){0.f, 0.f, 0.f, 0.f};
  int arow = m0 + (l & 15);
  if (arow >= nrows) arow = nrows - 1;
  const unsigned short* Ap = A + (size_t)arow * 128 + ((l >> 4) << 3);
#pragma unroll
  for (int kc = 0; kc < 4; kc++) {
    s8v av = *(const s8v*)(Ap + kc * 32);
#pragma unroll
    for (int nt = 0; nt < 8; nt++) {
      s8v bv = *(const s8v*)(Wf + (((size_t)(kc * 8 + nt)) << 9) + (l << 3));
      acc[nt] = __builtin_amdgcn_mfma_f32_16x16x32_bf16(av, bv, acc[nt], 0, 0, 0);
    }
  }
  float p[4] = {0.f, 0.f, 0.f, 0.f};
#pragma unroll
  for (int nt = 0; nt < 8; nt++) {
    int col = nt * 16 + (l & 15);
    float bi = bias[col], wv = w2v[col];
#pragma unroll
    for (int reg = 0; reg < 4; reg++)
      p[reg] = fmaf(fast_tanh(acc[nt][reg] + bi), wv, p[reg]);
  }
#pragma unroll
  for (int m = 1; m <= 8; m <<= 1)
#pragma unroll
    for (int reg = 0; reg < 4; reg++) p[reg] += __shfl_xor(p[reg], m);
  if ((l & 15) == 0) {
    float bb = b2[0];
#pragma unroll
    for (int reg = 0; reg < 4; reg++) {
      int row = m0 + ((l >> 4) << 2) + reg;
      if (row < nrows) scores[row] = p[reg] + bb;
    }
  }
}

// fused softmax + weighted sum
__global__ void k_attw(const float* __restrict__ sc, const unsigned short* __restrict__ hs,
                       unsigned short* __restrict__ nf) {
  int idx = blockIdx.x * 256 + threadIdx.x;
  if (idx >= BN_ * 64) return;
  int bn = idx >> 6, c = idx & 63;
  float v[T_];
  float m = -1e30f;
#pragma unroll
  for (int t = 0; t < T_; t++) { v[t] = sc[t * BN_ + bn]; m = fmaxf(m, v[t]); }
  float ssum = 0.f;
#pragma unroll
  for (int t = 0; t < T_; t++) { v[t] = __expf(v[t] - m); ssum += v[t]; }
  float inv = __builtin_amdgcn_rcpf(ssum);
  float s0 = 0.f, s1 = 0.f;
#pragma unroll
  for (int t = 0; t < T_; t++) {
    unsigned p = *(const unsigned*)(hs + ((size_t)t * BN_ + bn) * 128 + c * 2);
    float aw = v[t] * inv;
    s0 = fmaf(aw, bf2f((unsigned short)(p & 0xffffu)), s0);
    s1 = fmaf(aw, bf2f((unsigned short)(p >> 16)), s1);
  }
  *(unsigned*)(nf + (size_t)bn * 128 + c * 2) = pack2(s0, s1);
}

// fused GRU + step-0 projection
__global__ __launch_bounds__(256) void k_gruf(
    const unsigned short* __restrict__ A, const unsigned short* __restrict__ Wf,
    const float* __restrict__ bih, const float* __restrict__ bhh,
    float* __restrict__ hst, unsigned short* __restrict__ hbf,
    const float* __restrict__ ow, const float* __restrict__ ob,
    float* __restrict__ outp) {
  const int tid = threadIdx.x;
  const int l = tid & 63;
  const int w = tid >> 6;
  const int m0 = blockIdx.x * 64 + w * 16;

  f32x4 acc[24];
#pragma unroll
  for (int nt = 0; nt < 24; nt++) acc[nt] = (f32x4){0.f, 0.f, 0.f, 0.f};
  int arow = m0 + (l & 15);
  if (arow >= BN_) arow = BN_ - 1;
  const unsigned short* Ap = A + (size_t)arow * 128 + ((l >> 4) << 3);
#pragma unroll
  for (int kc = 0; kc < 4; kc++) {
    s8v av = *(const s8v*)(Ap + kc * 32);
#pragma unroll
    for (int nt = 0; nt < 24; nt++) {
      s8v bv = *(const s8v*)(Wf + (((size_t)(kc * 24 + nt)) << 9) + (l << 3));
      acc[nt] = __builtin_amdgcn_mfma_f32_16x16x32_bf16(av, bv, acc[nt], 0, 0, 0);
    }
  }
  const int hi = l >> 4, lo16 = l & 15;
  float p[4] = {0.f, 0.f, 0.f, 0.f};
#pragma unroll
  for (int nt = 0; nt < 8; nt++) {
    int col = nt * 16 + lo16;
    float br = bih[col], bz = bih[col + 128], bn = bih[col + 256];
    float hr = bhh[col], hz = bhh[col + 128], hn = bhh[col + 256];
    float owv = ow[col];
#pragma unroll
    for (int reg = 0; reg < 4; reg++) {
      int row = m0 + hi * 4 + reg;
      if (row >= BN_) continue;
      float r = fast_sigmoid(acc[nt][reg] + br + hr);
      float z = fast_sigmoid(acc[nt + 8][reg] + bz + hz);
      float n = fast_tanh(acc[nt + 16][reg] + bn + r * hn);
      float hv = (1.f - z) * n;  // h0 = 0
      size_t oi = (size_t)row * 128 + col;
      hst[oi] = hv;
      hbf[oi] = f2bf(hv);
      p[reg] = fmaf(hv, owv, p[reg]);
    }
  }
#pragma unroll
  for (int m = 1; m <= 8; m <<= 1)
#pragma unroll
    for (int reg = 0; reg < 4; reg++) p[reg] += __shfl_xor(p[reg], m);
  if (lo16 == 0) {
    float obv = ob[0];
#pragma unroll
    for (int reg = 0; reg < 4; reg++) {
      int row = m0 + hi * 4 + reg;
      if (row < BN_) outp[(size_t)row * FH_ + 0] = p[reg] + obv;
    }
  }
}

extern "C" void kernel_launch(void* const* d_in, const int* in_sizes, int n_in,
                              void* d_out, int out_size, void* d_ws, size_t ws_size,
                              hipStream_t stream) {
  const float* x       = (const float*)d_in[0];
  const float* gcn_w1  = (const float*)d_in[1];
  const float* gcn_b1  = (const float*)d_in[2];
  const float* gcn_w2  = (const float*)d_in[3];
  const float* gcn_b2  = (const float*)d_in[4];
  const float* gcn_w3  = (const float*)d_in[5];
  const float* gcn_b3  = (const float*)d_in[6];
  const float* att_w1  = (const float*)d_in[7];
  const float* att_b1  = (const float*)d_in[8];
  const float* att_w2  = (const float*)d_in[9];
  const float* att_b2  = (const float*)d_in[10];
  const float* gru_wih = (const float*)d_in[11];
  const float* gru_bih = (const float*)d_in[13];
  const float* gru_bhh = (const float*)d_in[14];
  const float* ode_w1  = (const float*)d_in[15];
  const float* ode_b1  = (const float*)d_in[16];
  const float* ode_w2  = (const float*)d_in[17];
  const float* ode_b2  = (const float*)d_in[18];
  const float* out_w   = (const float*)d_in[19];
  const float* out_b   = (const float*)d_in[20];
  const int*   eidx    = (const int*)d_in[21];
  float* out = (float*)d_out;

  float* wsf = (float*)d_ws;
  size_t off = 0;
  unsigned short* h1b12 = (unsigned short*)(wsf + off); off += (size_t)BN_ * 384;
  float* hst    = wsf + off; off += (size_t)BN_ * H_;
  float* scores = wsf + off; off += (size_t)T_ * BN_;
  float* dinv   = wsf + off; off += BN_;
  int2*  ev     = (int2*)(wsf + off); off += (size_t)EVCAP_ * 2;  // 16B-aligned
  unsigned short* hseqb  = (unsigned short*)(wsf + off); off += (size_t)T_ * BN_ * H_ / 2;
  unsigned short* t1b12  = (unsigned short*)(wsf + off); off += (size_t)T_ * BN_ * H_ / 2;
  unsigned short* hbf    = (unsigned short*)(wsf + off); off += (size_t)BN_ * H_ / 2;
  unsigned short* ubf    = (unsigned short*)(wsf + off); off += (size_t)BN_ * H_ / 2;
  unsigned short* rkb    = (unsigned short*)(wsf + off); off += (size_t)BN_ * H_ / 2;
  unsigned short* nfbf   = (unsigned short*)(wsf + off); off += (size_t)BN_ * H_ / 2;
  unsigned short* w2f    = (unsigned short*)(wsf + off); off += 64 * 128 / 2;
  unsigned short* w3f    = (unsigned short*)(wsf + off); off += 128 * 128 / 2;
  unsigned short* aw1f   = (unsigned short*)(wsf + off); off += 128 * 128 / 2;
  unsigned short* ow1f   = (unsigned short*)(wsf + off); off += 128 * 128 / 2;
  unsigned short* ow2f   = (unsigned short*)(wsf + off); off += 128 * 128 / 2;
  unsigned short* wihf   = (unsigned short*)(wsf + off); off += 128 * 384 / 2;
  int* rp   = (int*)(wsf + off); off += BN_ + 1;
  int* cnt  = (int*)(wsf + off); off += BN_;
  int* ord  = (int*)(wsf + off); off += BN_;
  int* hist = (int*)(wsf + off); off += 256;
  if (ws_size < off * sizeof(float)) {
    k_sentinel<<<1, 1, 0, stream>>>(out);
    return;
  }

  const int* esrc = eidx;
  const int* edst = eidx + E_;
  const int g79 = (BN_ + 255) / 256;

  // ---- CSR build (even-aligned rows, zeroed pads) + degree sort + weight prep ----
  hipMemsetAsync(ev, 0, (size_t)EVCAP_ * sizeof(int2), stream);
  hipMemsetAsync(hist, 0, 256 * sizeof(int), stream);
  k_init_cnt<<<g79, 256, 0, stream>>>(cnt);
  k_count<<<(E_ + 255) / 256, 256, 0, stream>>>(edst, cnt);
  k_scan<<<1, 1024, 0, stream>>>(cnt, rp, dinv);
  k_fill<<<(TOTE_ + 255) / 256, 256, 0, stream>>>(esrc, edst, rp, cnt, ev, dinv);
  k_hist<<<g79, 256, 0, stream>>>(rp, hist);
  k_binscan<<<1, 256, 0, stream>>>(hist);
  k_scatter<<<g79, 256, 0, stream>>>(rp, hist, ord);
  k_prep_all<<<480, 256, 0, stream>>>(gcn_w2, gcn_w3, att_w1, ode_w1, ode_w2, gru_wih,
                                      w2f, w3f, aw1f, ow1f, ow2f, wihf);

  const int gW = BN_ / 4;
  const int gR = (BN_ + 63) / 64;
  const int gF = 1280;

  // ---- spatial encoder: 3 dispatches for all 12 timesteps ----
  k_spl1T<<<gW, 256, 0, stream>>>(rp, ev, x, gcn_w1, gcn_b1, h1b12);
  k_fusedT<64><<<dim3(gF, 12), 256, 0, stream>>>(rp, ev, ord, h1b12, w2f, gcn_b2, t1b12);
  k_fusedT<128><<<dim3(gF, 12), 256, 0, stream>>>(rp, ev, ord, t1b12, w3f, gcn_b3, hseqb);

  // ---- temporal attention ----
  k_att<<<(T_ * BN_ + 63) / 64, 256, 0, stream>>>(hseqb, aw1f, att_b1, T_ * BN_,
                                                  att_w2, att_b2, scores);
  k_attw<<<(BN_ * 64 + 255) / 256, 256, 0, stream>>>(scores, hseqb, nfbf);

  // ---- GRU ----
  k_gruf<<<gR, 256, 0, stream>>>(nfbf, wihf, gru_bih, gru_bhh, hst, hbf,
                                 out_w, out_b, out);

  // ---- graph ODE, RK4: 2 fused dispatches per f-eval ----
  const float dt = (float)FH_ / (float)(FH_ - 1);
  unsigned short* t1 = t1b12;
  auto f_eval = [&](const unsigned short* inbf, int mode, float c1, float c2, int step) {
    k_fused<<<gF, 256, 0, stream>>>(rp, ev, ord, inbf, ow1f, ode_b1, 0, 0.f, 0.f,
                                    t1, nullptr, nullptr, nullptr, nullptr,
                                    nullptr, nullptr, nullptr, 0);
    k_fused<<<gF, 256, 0, stream>>>(rp, ev, ord, t1, ow2f, ode_b2, mode, c1, c2,
                                    nullptr, hbf, rkb, hst,
                                    (mode == 3) ? hbf : ubf,
                                    out_w, out_b, out, step);
  };
  for (int s = 1; s < FH_; s++) {
    f_eval(hbf, 1, 0.5f * dt, 0.f, s);
    f_eval(ubf, 2, 0.5f * dt, 0.f, s);
    f_eval(ubf, 2, dt, 0.f, s);
    f_eval(ubf, 3, 0.f, dt / 6.f, s);
  }
}

// Round 10
// 1768.187 us; speedup vs baseline: 1.3663x; 1.3663x over previous
//
#include <hip/hip_runtime.h>
#include <stdint.h>

#define B_ 4
#define N_ 5000
#define T_ 12
#define FH_ 12
#define H_ 128
#define BN_ 20000
#define E_ 320000
#define TOTE_ (E_ + BN_)
#define EVCAP_ (TOTE_ + BN_)   // CSR with even-alignment pads
#define EDCAP_ 360448          // packed per-tile edge list capacity (entries)
#define NTB_ 313               // 16-row tiles per batch
#define NT_ 1252               // total tiles
#define SLOTB_ 5008            // slots per batch (NTB_*16)
#define BNS_ 20032             // total slots

typedef __attribute__((ext_vector_type(8))) short s8v;
typedef __attribute__((ext_vector_type(4))) float f32x4;

__device__ __forceinline__ float fast_tanh(float x) {
  float e = __expf(2.f * x);
  return 1.f - 2.f * __builtin_amdgcn_rcpf(e + 1.f);
}
__device__ __forceinline__ float fast_sigmoid(float x) {
  return __builtin_amdgcn_rcpf(1.f + __expf(-x));
}
__device__ __forceinline__ unsigned short f2bf(float f) {  // RNE
  unsigned u = __float_as_uint(f);
  u = (u + 0x7fffu + ((u >> 16) & 1u)) >> 16;
  return (unsigned short)u;
}
__device__ __forceinline__ float bf2f(unsigned short u) {
  return __uint_as_float(((unsigned)u) << 16);
}
__device__ __forceinline__ unsigned pack2(float lo, float hi) {
  return ((unsigned)f2bf(hi) << 16) | f2bf(lo);
}

__global__ void k_sentinel(float* out) { out[0] = 1e30f; }

__global__ void k_init_cnt(int* cnt) {
  int i = blockIdx.x * 256 + threadIdx.x;
  if (i < BN_) cnt[i] = 1;  // self-loop
}
__global__ void k_count(const int* __restrict__ dst, int* cnt) {
  int e = blockIdx.x * 256 + threadIdx.x;
  if (e < E_) atomicAdd(&cnt[dst[e]], 1);
}
// exclusive scan of cnt -> rp (row starts EVEN-aligned), dinv=rsqrt(cnt); zero cnt
__global__ void k_scan(int* cnt, int* rp, float* dinv) {
  __shared__ int sh[1024];
  int tid = threadIdx.x;
  const int per = (BN_ + 1023) / 1024;
  int start = tid * per;
  int end = start + per; if (end > BN_) end = BN_;
  int s = 0;
  for (int i = start; i < end; i++) {
    int c = cnt[i];
    dinv[i] = rsqrtf((float)c);
    s += (c + 1) & ~1;
  }
  sh[tid] = s;
  __syncthreads();
  for (int off = 1; off < 1024; off <<= 1) {
    int v = (tid >= off) ? sh[tid - off] : 0;
    __syncthreads();
    sh[tid] += v;
    __syncthreads();
  }
  int run = (tid > 0) ? sh[tid - 1] : 0;
  for (int i = start; i < end; i++) {
    int c = cnt[i];
    rp[i] = run;
    run += (c + 1) & ~1;
    cnt[i] = 0;
  }
  if (tid == 1023) rp[BN_] = sh[1023];
}
// ev[pos] = {src*128, bits(dinv[s]*dinv[d])}; pad slots stay zero (memset)
__global__ void k_fill(const int* __restrict__ src, const int* __restrict__ dst,
                       const int* __restrict__ rp, int* cnt, int2* ev,
                       const float* __restrict__ dinv) {
  int e = blockIdx.x * 256 + threadIdx.x;
  if (e >= TOTE_) return;
  int s, d;
  if (e < E_) { s = src[e]; d = dst[e]; }
  else { s = d = e - E_; }
  int pos = rp[d] + atomicAdd(&cnt[d], 1);
  int2 p; p.x = s * 128; p.y = __float_as_int(dinv[s] * dinv[d]);
  ev[pos] = p;
}

// ---- degree sort (per batch, DESCENDING) + inverse permutation ----
__global__ void k_hist(const int* __restrict__ rp, int* hist) {
  int i = blockIdx.x * 256 + threadIdx.x;
  if (i < BN_) {
    int d = (rp[i + 1] - rp[i]) >> 1; d = d > 63 ? 63 : d;
    atomicAdd(&hist[(i / N_) * 64 + (63 - d)], 1);
  }
}
__global__ void k_binscan(int* hist) {
  __shared__ int sh[256];
  int t = threadIdx.x;
  int val = hist[t];
  sh[t] = val;
  __syncthreads();
  for (int o = 1; o < 256; o <<= 1) {
    int v = (t >= o) ? sh[t - o] : 0;
    __syncthreads();
    sh[t] += v;
    __syncthreads();
  }
  hist[t] = sh[t] - val;
}
__global__ void k_scatter(const int* __restrict__ rp, int* hist, int* ord, int* posj) {
  int i = blockIdx.x * 256 + threadIdx.x;
  if (i < BN_) {
    int d = (rp[i + 1] - rp[i]) >> 1; d = d > 63 ? 63 : d;
    int gpos = atomicAdd(&hist[(i / N_) * 64 + (63 - d)], 1);
    ord[gpos] = i;
    posj[i] = gpos - (i / N_) * N_;  // within-batch sorted index
  }
}

// per-tile row pair-offsets + tile pair counts
__global__ void k_rowoff(const int* __restrict__ rp, const int* __restrict__ ord,
                         int* rowoffp, int* tcntp) {
  int t = blockIdx.x * 256 + threadIdx.x;
  if (t >= NT_) return;
  int bb = t / NTB_, within = t % NTB_;
  int acc = 0;
  for (int r = 0; r < 16; r++) {
    int j = within * 16 + r;
    int plen = 0;
    if (j < N_) {
      int row = ord[bb * N_ + j];
      plen = (rp[row + 1] - rp[row]) >> 1;
    }
    rowoffp[t * 16 + r] = acc;
    acc += plen;
  }
  tcntp[t] = acc;
}
__global__ void k_tscan(const int* __restrict__ tcnt, int* __restrict__ tstart) {
  __shared__ int sh[1024];
  int tid = threadIdx.x;
  int st = tid * 2, en = st + 2; if (en > NT_) en = NT_;
  int s = 0;
  for (int i = st; i < en; i++) s += tcnt[i];
  sh[tid] = s;
  __syncthreads();
  for (int o = 1; o < 1024; o <<= 1) {
    int v = (tid >= o) ? sh[tid - o] : 0;
    __syncthreads();
    sh[tid] += v;
    __syncthreads();
  }
  int run = tid ? sh[tid - 1] : 0;
  for (int i = st; i < en; i++) { tstart[i] = run; run += tcnt[i]; }
  if (tid == 1023) tstart[NT_] = sh[1023];
}
// packed per-tile edge list: {slot(src), w}; pads copied from ev (w=0)
__global__ void k_edfill(const int* __restrict__ rp, const int* __restrict__ ord,
                         const int* __restrict__ posj, const int2* __restrict__ ev,
                         const int* __restrict__ tstartp, const int* __restrict__ rowoffp,
                         int2* __restrict__ ed) {
  int idx = blockIdx.x * 256 + threadIdx.x;
  if (idx >= NT_ * 16) return;
  int t = idx >> 4, r = idx & 15;
  int bb = t / NTB_, within = t % NTB_;
  int j = within * 16 + r;
  if (j >= N_) return;
  int row = ord[bb * N_ + j];
  int b0 = rp[row], len = rp[row + 1] - b0;  // padded even
  int dst = (tstartp[t] + rowoffp[t * 16 + r]) * 2;
  for (int i = 0; i < len; i++) {
    int2 p = ev[b0 + i];
    int src = p.x >> 7;
    int2 o; o.x = (src / N_) * SLOTB_ + posj[src]; o.y = p.y;
    ed[dst + i] = o;
  }
}

// MFMA B-frag pack
__device__ __forceinline__ void prep_one(const float* __restrict__ src,
                                         unsigned short* __restrict__ dst,
                                         int K, int Nn, int transposed, int idx) {
  int j = idx & 7, l = (idx >> 3) & 63, rest = idx >> 9;
  int NT = Nn >> 4;
  int nt = rest % NT, kc = rest / NT;
  int k = kc * 32 + ((l >> 4) << 3) + j;
  int n = nt * 16 + (l & 15);
  float v = transposed ? src[n * K + k] : src[k * Nn + n];
  dst[idx] = f2bf(v);
}
__global__ void k_prep_all(const float* w2, const float* w3, const float* a1,
                           const float* o1, const float* o2, const float* wih,
                           unsigned short* w2f, unsigned short* w3f, unsigned short* a1f,
                           unsigned short* o1f, unsigned short* o2f, unsigned short* wihf) {
  int idx = blockIdx.x * 256 + threadIdx.x;
  if (idx < 8192) { prep_one(w2, w2f, 64, 128, 0, idx); return; }
  idx -= 8192;
  if (idx < 16384) { prep_one(w3, w3f, 128, 128, 0, idx); return; }
  idx -= 16384;
  if (idx < 16384) { prep_one(a1, a1f, 128, 128, 0, idx); return; }
  idx -= 16384;
  if (idx < 16384) { prep_one(o1, o1f, 128, 128, 0, idx); return; }
  idx -= 16384;
  if (idx < 16384) { prep_one(o2, o2f, 128, 128, 0, idx); return; }
  idx -= 16384;
  if (idx < 49152) prep_one(wih, wihf, 128, 384, 1, idx);
}

// all-T layer1; stores into slot order
__global__ void k_spl1T(const int* __restrict__ rp, const int2* __restrict__ ev,
                        const int* __restrict__ posj,
                        const float* __restrict__ x,
                        const float* __restrict__ w1, const float* __restrict__ b1,
                        unsigned short* __restrict__ h1) {
  int wid = (blockIdx.x * 256 + threadIdx.x) >> 6;
  int lane = threadIdx.x & 63;
  if (wid >= BN_) return;
  int beg = rp[wid], end = rp[wid + 1];
  float a[12];
#pragma unroll
  for (int t = 0; t < 12; t++) a[t] = 0.f;
  for (int e = beg + lane; e < end; e += 64) {
    int2 p = ev[e];
    const float4* xp = (const float4*)(x + (size_t)(p.x >> 7) * 12);
    float v = __int_as_float(p.y);
    float4 x0 = xp[0], x1 = xp[1], x2 = xp[2];
    a[0] = fmaf(v, x0.x, a[0]);  a[1] = fmaf(v, x0.y, a[1]);
    a[2] = fmaf(v, x0.z, a[2]);  a[3] = fmaf(v, x0.w, a[3]);
    a[4] = fmaf(v, x1.x, a[4]);  a[5] = fmaf(v, x1.y, a[5]);
    a[6] = fmaf(v, x1.z, a[6]);  a[7] = fmaf(v, x1.w, a[7]);
    a[8] = fmaf(v, x2.x, a[8]);  a[9] = fmaf(v, x2.y, a[9]);
    a[10] = fmaf(v, x2.z, a[10]); a[11] = fmaf(v, x2.w, a[11]);
  }
#pragma unroll
  for (int t = 0; t < 12; t++)
#pragma unroll
    for (int m = 1; m < 64; m <<= 1) a[t] += __shfl_xor(a[t], m);
  float wv = w1[lane], bv = b1[lane];
  int slot = (wid / N_) * SLOTB_ + posj[wid];
#pragma unroll
  for (int t = 0; t < 12; t++) {
    float v = fmaf(a[t], wv, bv);
    h1[((size_t)t * BNS_ + slot) * 64 + lane] = f2bf(fmaxf(v, 0.f));
  }
}

// ---- LDS-descriptor 4-way edge-split gather (slot-order input) ----
template<int KIN>
__device__ __forceinline__ void gather_tile(
    const int2* __restrict__ ed, const int* __restrict__ tstartp,
    const int* __restrict__ rowoffp, const unsigned short* __restrict__ in,
    unsigned short (*agg)[KIN + 8], uint4* desc, int tileid, int w, int l, int tid) {
  constexpr int SH = (KIN == 128) ? 7 : 6;
  constexpr int CW = KIN / 16;
  const int h = l >> 4, c = l & 15;
  const unsigned short* inc = in + c * CW;
  int tp0 = tstartp[tileid];
  int npair = tstartp[tileid + 1] - tp0;
  const uint4* edp = (const uint4*)(ed + (size_t)tp0 * 2);
  for (int i = tid; i < npair; i += 256) desc[i] = edp[i];
  __syncthreads();
  int q0[4], qlen[4];
  float a[4][CW];
  int mx = 0;
  const int* rot = rowoffp + tileid * 16;
#pragma unroll
  for (int r = 0; r < 4; r++) {
    int lr = w * 4 + r;
    int ro = rot[lr];
    int rn = (lr == 15) ? npair : rot[lr + 1];
    int lenp = rn - ro;
    int s0 = (lenp * h) >> 2, s1 = (lenp * (h + 1)) >> 2;
    q0[r] = ro + s0;
    qlen[r] = s1 - s0;
    mx = qlen[r] > mx ? qlen[r] : mx;
#pragma unroll
    for (int q = 0; q < CW; q++) a[r][q] = 0.f;
  }
  int lim = npair - 1;
  for (int i = 0; i < mx; i++) {
#pragma unroll
    for (int r = 0; r < 4; r++) {
      int idx = q0[r] + i; idx = idx > lim ? lim : idx;
      uint4 d = desc[idx];                // unguarded LDS read (pipelinable)
      if (i < qlen[r]) {
        float vA = __int_as_float(d.y), vB = __int_as_float(d.w);
        if (KIN == 128) {
          uint4 pA = *(const uint4*)(inc + ((size_t)d.x << SH));
          uint4 pB = *(const uint4*)(inc + ((size_t)d.z << SH));
          a[r][0] = fmaf(vA, bf2f((unsigned short)(pA.x & 0xffffu)), a[r][0]);
          a[r][1] = fmaf(vA, bf2f((unsigned short)(pA.x >> 16)), a[r][1]);
          a[r][2] = fmaf(vA, bf2f((unsigned short)(pA.y & 0xffffu)), a[r][2]);
          a[r][3] = fmaf(vA, bf2f((unsigned short)(pA.y >> 16)), a[r][3]);
          a[r][4] = fmaf(vA, bf2f((unsigned short)(pA.z & 0xffffu)), a[r][4]);
          a[r][5] = fmaf(vA, bf2f((unsigned short)(pA.z >> 16)), a[r][5]);
          a[r][6] = fmaf(vA, bf2f((unsigned short)(pA.w & 0xffffu)), a[r][6]);
          a[r][7] = fmaf(vA, bf2f((unsigned short)(pA.w >> 16)), a[r][7]);
          a[r][0] = fmaf(vB, bf2f((unsigned short)(pB.x & 0xffffu)), a[r][0]);
          a[r][1] = fmaf(vB, bf2f((unsigned short)(pB.x >> 16)), a[r][1]);
          a[r][2] = fmaf(vB, bf2f((unsigned short)(pB.y & 0xffffu)), a[r][2]);
          a[r][3] = fmaf(vB, bf2f((unsigned short)(pB.y >> 16)), a[r][3]);
          a[r][4] = fmaf(vB, bf2f((unsigned short)(pB.z & 0xffffu)), a[r][4]);
          a[r][5] = fmaf(vB, bf2f((unsigned short)(pB.z >> 16)), a[r][5]);
          a[r][6] = fmaf(vB, bf2f((unsigned short)(pB.w & 0xffffu)), a[r][6]);
          a[r][7] = fmaf(vB, bf2f((unsigned short)(pB.w >> 16)), a[r][7]);
        } else {
          uint2 pA = *(const uint2*)(inc + ((size_t)d.x << SH));
          uint2 pB = *(const uint2*)(inc + ((size_t)d.z << SH));
          a[r][0] = fmaf(vA, bf2f((unsigned short)(pA.x & 0xffffu)), a[r][0]);
          a[r][1] = fmaf(vA, bf2f((unsigned short)(pA.x >> 16)), a[r][1]);
          a[r][2] = fmaf(vA, bf2f((unsigned short)(pA.y & 0xffffu)), a[r][2]);
          a[r][3] = fmaf(vA, bf2f((unsigned short)(pA.y >> 16)), a[r][3]);
          a[r][0] = fmaf(vB, bf2f((unsigned short)(pB.x & 0xffffu)), a[r][0]);
          a[r][1] = fmaf(vB, bf2f((unsigned short)(pB.x >> 16)), a[r][1]);
          a[r][2] = fmaf(vB, bf2f((unsigned short)(pB.y & 0xffffu)), a[r][2]);
          a[r][3] = fmaf(vB, bf2f((unsigned short)(pB.y >> 16)), a[r][3]);
        }
      }
    }
  }
#pragma unroll
  for (int r = 0; r < 4; r++) {
#pragma unroll
    for (int q2 = 0; q2 < CW; q2++) {
      a[r][q2] += __shfl_xor(a[r][q2], 16);
      a[r][q2] += __shfl_xor(a[r][q2], 32);
    }
    if (h == 0) {
      if (KIN == 128) {
        uint4 o;
        o.x = pack2(a[r][0], a[r][1]); o.y = pack2(a[r][2], a[r][3]);
        o.z = pack2(a[r][4], a[r][5]); o.w = pack2(a[r][6], a[r][7]);
        *(uint4*)&agg[w * 4 + r][c * 8] = o;
      } else {
        uint2 o;
        o.x = pack2(a[r][0], a[r][1]); o.y = pack2(a[r][2], a[r][3]);
        *(uint2*)&agg[w * 4 + r][c * 4] = o;
      }
    }
  }
}

template<int KIN>
__device__ __forceinline__ void mfma_tile(
    const unsigned short (*agg)[KIN + 8], const unsigned short* __restrict__ Wf,
    int w, int l, f32x4 acc[2]) {
  constexpr int KC = KIN / 32;
  const int hi = l >> 4, lo16 = l & 15;
  acc[0] = (f32x4){0.f, 0.f, 0.f, 0.f};
  acc[1] = (f32x4){0.f, 0.f, 0.f, 0.f};
#pragma unroll
  for (int kc = 0; kc < KC; kc++) {
    s8v av = *(const s8v*)&agg[lo16][kc * 32 + hi * 8];
#pragma unroll
    for (int q = 0; q < 2; q++) {
      s8v bv = *(const s8v*)(Wf + (((size_t)(kc * 8 + 2 * w + q)) << 9) + (l << 3));
      acc[q] = __builtin_amdgcn_mfma_f32_16x16x32_bf16(av, bv, acc[q], 0, 0, 0);
    }
  }
}

// spatial fused SpMM+GEMM (relu), batched over t = blockIdx.y; slot-linear I/O
template<int KIN>
__global__ __launch_bounds__(256) void k_fusedT(
    const int2* __restrict__ ed, const int* __restrict__ tstartp,
    const int* __restrict__ rowoffp,
    const unsigned short* __restrict__ inb, const unsigned short* __restrict__ Wf,
    const float* __restrict__ bias, unsigned short* __restrict__ outb) {
  __shared__ __align__(16) uint4 desc[512];
  __shared__ unsigned short agg[16][KIN + 8];
  const int tid = threadIdx.x, l = tid & 63, w = tid >> 6;
  const int t = blockIdx.y;
  const unsigned short* in = inb + (size_t)t * BNS_ * KIN;
  unsigned short* out = outb + (size_t)t * BNS_ * 128;
  const int bid = blockIdx.x;
  const int xcd = bid & 7, slot = bid >> 3;
  const int bb = xcd >> 1;
  const int within = slot * 2 + (xcd & 1);
  if (within >= NTB_) return;
  int nv = N_ - within * 16; nv = nv > 16 ? 16 : nv;
  const int tileid = bb * NTB_ + within;
  gather_tile<KIN>(ed, tstartp, rowoffp, in, agg, desc, tileid, w, l, tid);
  __syncthreads();
  f32x4 acc[2];
  mfma_tile<KIN>(agg, Wf, w, l, acc);
  const int hi = l >> 4, lo16 = l & 15;
  const int rowbase = tileid * 16;
#pragma unroll
  for (int q = 0; q < 2; q++) {
    int col = (2 * w + q) * 16 + lo16;
    float bi = bias[col];
#pragma unroll
    for (int reg = 0; reg < 4; reg++) {
      int lr = hi * 4 + reg;
      if (lr < nv)
        out[(size_t)(rowbase + lr) * 128 + col] = f2bf(fmaxf(acc[q][reg] + bi, 0.f));
    }
  }
}

// ODE fused SpMM+GEMM+epilogue (KIN=128), slot-linear state tensors
__global__ __launch_bounds__(256) void k_fused(
    const int2* __restrict__ ed, const int* __restrict__ tstartp,
    const int* __restrict__ rowoffp, const int* __restrict__ ord,
    const unsigned short* __restrict__ in,
    const unsigned short* __restrict__ Wf, const float* __restrict__ bias,
    int mode, float c1, float c2,
    unsigned short* __restrict__ outb,
    const unsigned short* __restrict__ hbfin, unsigned short* __restrict__ rkb,
    float* __restrict__ h, unsigned short* __restrict__ ubfout,
    const float* __restrict__ ow, const float* __restrict__ ob,
    float* __restrict__ outp, int step) {
  __shared__ __align__(16) uint4 desc[512];
  __shared__ unsigned short agg[16][136];
  __shared__ float ppart[4][16];
  const int tid = threadIdx.x, l = tid & 63, w = tid >> 6;
  const int bid = blockIdx.x;
  const int xcd = bid & 7, slot = bid >> 3;
  const int bb = xcd >> 1;
  const int within = slot * 2 + (xcd & 1);
  if (within >= NTB_) return;
  int nv = N_ - within * 16; nv = nv > 16 ? 16 : nv;
  const int tileid = bb * NTB_ + within;
  gather_tile<128>(ed, tstartp, rowoffp, in, agg, desc, tileid, w, l, tid);
  __syncthreads();
  f32x4 acc[2];
  mfma_tile<128>(agg, Wf, w, l, acc);
  const int hi = l >> 4, lo16 = l & 15;
  const int rowbase = tileid * 16;
  float p[4] = {0.f, 0.f, 0.f, 0.f};
#pragma unroll
  for (int q = 0; q < 2; q++) {
    int col = (2 * w + q) * 16 + lo16;
    float bi = bias[col];
    float owv = (mode == 3) ? ow[col] : 0.f;
#pragma unroll
    for (int reg = 0; reg < 4; reg++) {
      int lr = hi * 4 + reg;
      if (lr >= nv) continue;
      size_t oi = (size_t)(rowbase + lr) * 128 + col;
      float v = fast_tanh(acc[q][reg] + bi);
      if (mode == 0) {
        outb[oi] = f2bf(v);
      } else if (mode == 1) {
        rkb[oi] = f2bf(v);
        ubfout[oi] = f2bf(fmaf(c1, v, bf2f(hbfin[oi])));
      } else if (mode == 2) {
        rkb[oi] = f2bf(bf2f(rkb[oi]) + 2.f * v);
        ubfout[oi] = f2bf(fmaf(c1, v, bf2f(hbfin[oi])));
      } else {
        float nh = fmaf(c2, bf2f(rkb[oi]) + v, h[oi]);
        h[oi] = nh;
        ubfout[oi] = f2bf(nh);
        p[reg] = fmaf(nh, owv, p[reg]);
      }
    }
  }
  if (mode == 3) {
#pragma unroll
    for (int m = 1; m <= 8; m <<= 1)
#pragma unroll
      for (int reg = 0; reg < 4; reg++) p[reg] += __shfl_xor(p[reg], m);
    if (lo16 == 0)
#pragma unroll
      for (int reg = 0; reg < 4; reg++) ppart[w][hi * 4 + reg] = p[reg];
    __syncthreads();
    if (tid < 16 && tid < nv) {
      int orig = ord[bb * N_ + within * 16 + tid];
      outp[(size_t)orig * FH_ + step] =
          ppart[0][tid] + ppart[1][tid] + ppart[2][tid] + ppart[3][tid] + ob[0];
    }
  }
}

// attention scores (rows = 12*BNS_ slots)
__global__ __launch_bounds__(256) void k_att(
    const unsigned short* __restrict__ A, const unsigned short* __restrict__ Wf,
    const float* __restrict__ bias, int nrows,
    const float* __restrict__ w2v, const float* __restrict__ b2,
    float* __restrict__ scores) {
  const int tid = threadIdx.x;
  const int l = tid & 63;
  const int w = tid >> 6;
  const int m0 = blockIdx.x * 64 + w * 16;

  f32x4 acc[8];
#pragma unroll
  for (int nt = 0; nt < 8; nt++) acc[nt] = (f32x4){0.f, 0.f, 0.f, 0.f};
  int arow = m0 + (l & 15);
  if (arow >= nrows) arow = nrows - 1;
  const unsigned short* Ap = A + (size_t)arow * 128 + ((l >> 4) << 3);
#pragma unroll
  for (int kc = 0; kc < 4; kc++) {
    s8v av = *(const s8v*)(Ap + kc * 32);
#pragma unroll
    for (int nt = 0; nt < 8; nt++) {
      s8v bv = *(const s8v*)(Wf + (((size_t)(kc * 8 + nt)) << 9) + (l << 3));
      acc[nt] = __builtin_amdgcn_mfma_f32_16x16x32_bf16(av, bv, acc[nt], 0, 0, 0);
    }
  }
  float p[4] = {0.f, 0.f, 0.f, 0.f};
#pragma unroll
  for (int nt = 0; nt < 8; nt++) {
    int col = nt * 16 + (l & 15);
    float bi = bias[col], wv = w2v[col];
#pragma unroll
    for (int reg = 0; reg < 4; reg++)
      p[reg] = fmaf(fast_tanh(acc[nt][reg] + bi), wv, p[reg]);
  }
#pragma unroll
  for (int m = 1; m <= 8; m <<= 1)
#pragma unroll
    for (int reg = 0; reg < 4; reg++) p[reg] += __shfl_xor(p[reg], m);
  if ((l & 15) == 0) {
    float bb = b2[0];
#pragma unroll
    for (int reg = 0; reg < 4; reg++) {
      int row = m0 + ((l >> 4) << 2) + reg;
      if (row < nrows) scores[row] = p[reg] + bb;
    }
  }
}

// fused softmax + weighted sum over slots
__global__ void k_attw(const float* __restrict__ sc, const unsigned short* __restrict__ hs,
                       unsigned short* __restrict__ nf) {
  int idx = blockIdx.x * 256 + threadIdx.x;
  if (idx >= BNS_ * 64) return;
  int bn = idx >> 6, c = idx & 63;
  float v[T_];
  float m = -1e30f;
#pragma unroll
  for (int t = 0; t < T_; t++) { v[t] = sc[t * BNS_ + bn]; m = fmaxf(m, v[t]); }
  float ssum = 0.f;
#pragma unroll
  for (int t = 0; t < T_; t++) { v[t] = __expf(v[t] - m); ssum += v[t]; }
  float inv = __builtin_amdgcn_rcpf(ssum);
  float s0 = 0.f, s1 = 0.f;
#pragma unroll
  for (int t = 0; t < T_; t++) {
    unsigned p = *(const unsigned*)(hs + ((size_t)t * BNS_ + bn) * 128 + c * 2);
    float aw = v[t] * inv;
    s0 = fmaf(aw, bf2f((unsigned short)(p & 0xffffu)), s0);
    s1 = fmaf(aw, bf2f((unsigned short)(p >> 16)), s1);
  }
  *(unsigned*)(nf + (size_t)bn * 128 + c * 2) = pack2(s0, s1);
}

// fused GRU + step-0 projection (slot-order; un-permute via ord for outp)
__global__ __launch_bounds__(256) void k_gruf(
    const unsigned short* __restrict__ A, const unsigned short* __restrict__ Wf,
    const float* __restrict__ bih, const float* __restrict__ bhh,
    const int* __restrict__ ord,
    float* __restrict__ hst, unsigned short* __restrict__ hbf,
    const float* __restrict__ ow, const float* __restrict__ ob,
    float* __restrict__ outp) {
  const int tid = threadIdx.x;
  const int l = tid & 63;
  const int w = tid >> 6;
  const int m0 = blockIdx.x * 64 + w * 16;

  f32x4 acc[24];
#pragma unroll
  for (int nt = 0; nt < 24; nt++) acc[nt] = (f32x4){0.f, 0.f, 0.f, 0.f};
  int arow = m0 + (l & 15);
  const unsigned short* Ap = A + (size_t)arow * 128 + ((l >> 4) << 3);
#pragma unroll
  for (int kc = 0; kc < 4; kc++) {
    s8v av = *(const s8v*)(Ap + kc * 32);
#pragma unroll
    for (int nt = 0; nt < 24; nt++) {
      s8v bv = *(const s8v*)(Wf + (((size_t)(kc * 24 + nt)) << 9) + (l << 3));
      acc[nt] = __builtin_amdgcn_mfma_f32_16x16x32_bf16(av, bv, acc[nt], 0, 0, 0);
    }
  }
  const int hi = l >> 4, lo16 = l & 15;
  float p[4] = {0.f, 0.f, 0.f, 0.f};
#pragma unroll
  for (int nt = 0; nt < 8; nt++) {
    int col = nt * 16 + lo16;
    float br = bih[col], bz = bih[col + 128], bn = bih[col + 256];
    float hr = bhh[col], hz = bhh[col + 128], hn = bhh[col + 256];
    float owv = ow[col];
#pragma unroll
    for (int reg = 0; reg < 4; reg++) {
      int slot = m0 + hi * 4 + reg;
      float r = fast_sigmoid(acc[nt][reg] + br + hr);
      float z = fast_sigmoid(acc[nt + 8][reg] + bz + hz);
      float n = fast_tanh(acc[nt + 16][reg] + bn + r * hn);
      float hv = (1.f - z) * n;  // h0 = 0
      size_t oi = (size_t)slot * 128 + col;
      hst[oi] = hv;
      hbf[oi] = f2bf(hv);
      p[reg] = fmaf(hv, owv, p[reg]);
    }
  }
#pragma unroll
  for (int m = 1; m <= 8; m <<= 1)
#pragma unroll
    for (int reg = 0; reg < 4; reg++) p[reg] += __shfl_xor(p[reg], m);
  if (lo16 == 0) {
    float obv = ob[0];
#pragma unroll
    for (int reg = 0; reg < 4; reg++) {
      int slot = m0 + hi * 4 + reg;
      int bbv = slot / SLOTB_;
      int j = slot - bbv * SLOTB_;
      if (j < N_) {
        int orig = ord[bbv * N_ + j];
        outp[(size_t)orig * FH_ + 0] = p[reg] + obv;
      }
    }
  }
}

extern "C" void kernel_launch(void* const* d_in, const int* in_sizes, int n_in,
                              void* d_out, int out_size, void* d_ws, size_t ws_size,
                              hipStream_t stream) {
  const float* x       = (const float*)d_in[0];
  const float* gcn_w1  = (const float*)d_in[1];
  const float* gcn_b1  = (const float*)d_in[2];
  const float* gcn_w2  = (const float*)d_in[3];
  const float* gcn_b2  = (const float*)d_in[4];
  const float* gcn_w3  = (const float*)d_in[5];
  const float* gcn_b3  = (const float*)d_in[6];
  const float* att_w1  = (const float*)d_in[7];
  const float* att_b1  = (const float*)d_in[8];
  const float* att_w2  = (const float*)d_in[9];
  const float* att_b2  = (const float*)d_in[10];
  const float* gru_wih = (const float*)d_in[11];
  const float* gru_bih = (const float*)d_in[13];
  const float* gru_bhh = (const float*)d_in[14];
  const float* ode_w1  = (const float*)d_in[15];
  const float* ode_b1  = (const float*)d_in[16];
  const float* ode_w2  = (const float*)d_in[17];
  const float* ode_b2  = (const float*)d_in[18];
  const float* out_w   = (const float*)d_in[19];
  const float* out_b   = (const float*)d_in[20];
  const int*   eidx    = (const int*)d_in[21];
  float* out = (float*)d_out;

  float* wsf = (float*)d_ws;
  size_t off = 0;
  unsigned short* h1b12 = (unsigned short*)(wsf + off); off += (size_t)12 * BNS_ * 32;
  float* hst    = wsf + off; off += (size_t)BNS_ * H_;
  float* scores = wsf + off; off += (size_t)T_ * BNS_;
  float* dinv   = wsf + off; off += BN_;
  int2*  ev     = (int2*)(wsf + off); off += (size_t)EVCAP_ * 2;   // 16B-aligned
  int2*  ed     = (int2*)(wsf + off); off += (size_t)EDCAP_ * 2;   // 16B-aligned
  unsigned short* hseqb  = (unsigned short*)(wsf + off); off += (size_t)T_ * BNS_ * 64;
  unsigned short* t1b12  = (unsigned short*)(wsf + off); off += (size_t)T_ * BNS_ * 64;
  unsigned short* hbf    = (unsigned short*)(wsf + off); off += (size_t)BNS_ * 64;
  unsigned short* ubf    = (unsigned short*)(wsf + off); off += (size_t)BNS_ * 64;
  unsigned short* rkb    = (unsigned short*)(wsf + off); off += (size_t)BNS_ * 64;
  unsigned short* nfbf   = (unsigned short*)(wsf + off); off += (size_t)BNS_ * 64;
  unsigned short* w2f    = (unsigned short*)(wsf + off); off += 64 * 128 / 2;
  unsigned short* w3f    = (unsigned short*)(wsf + off); off += 128 * 128 / 2;
  unsigned short* aw1f   = (unsigned short*)(wsf + off); off += 128 * 128 / 2;
  unsigned short* ow1f   = (unsigned short*)(wsf + off); off += 128 * 128 / 2;
  unsigned short* ow2f   = (unsigned short*)(wsf + off); off += 128 * 128 / 2;
  unsigned short* wihf   = (unsigned short*)(wsf + off); off += 128 * 384 / 2;
  int* rp      = (int*)(wsf + off); off += BN_ + 1;
  int* cnt     = (int*)(wsf + off); off += BN_;
  int* ord     = (int*)(wsf + off); off += BN_;
  int* posj    = (int*)(wsf + off); off += BN_;
  int* hist    = (int*)(wsf + off); off += 256;
  int* rowoffp = (int*)(wsf + off); off += (size_t)NT_ * 16;
  int* tcntp   = (int*)(wsf + off); off += NT_;
  int* tstartp = (int*)(wsf + off); off += NT_ + 1;
  if (ws_size < off * sizeof(float)) {
    k_sentinel<<<1, 1, 0, stream>>>(out);
    return;
  }

  const int* esrc = eidx;
  const int* edst = eidx + E_;
  const int g79 = (BN_ + 255) / 256;

  // ---- CSR + degree sort + packed tile edge list + weight prep ----
  hipMemsetAsync(ev, 0, (size_t)EVCAP_ * sizeof(int2), stream);
  hipMemsetAsync(hist, 0, 256 * sizeof(int), stream);
  k_init_cnt<<<g79, 256, 0, stream>>>(cnt);
  k_count<<<(E_ + 255) / 256, 256, 0, stream>>>(edst, cnt);
  k_scan<<<1, 1024, 0, stream>>>(cnt, rp, dinv);
  k_fill<<<(TOTE_ + 255) / 256, 256, 0, stream>>>(esrc, edst, rp, cnt, ev, dinv);
  k_hist<<<g79, 256, 0, stream>>>(rp, hist);
  k_binscan<<<1, 256, 0, stream>>>(hist);
  k_scatter<<<g79, 256, 0, stream>>>(rp, hist, ord, posj);
  k_rowoff<<<(NT_ + 255) / 256, 256, 0, stream>>>(rp, ord, rowoffp, tcntp);
  k_tscan<<<1, 1024, 0, stream>>>(tcntp, tstartp);
  k_edfill<<<(NT_ * 16 + 255) / 256, 256, 0, stream>>>(rp, ord, posj, ev,
                                                       tstartp, rowoffp, ed);
  k_prep_all<<<480, 256, 0, stream>>>(gcn_w2, gcn_w3, att_w1, ode_w1, ode_w2, gru_wih,
                                      w2f, w3f, aw1f, ow1f, ow2f, wihf);

  const int gW = BN_ / 4;
  const int gF = 1280;

  // ---- spatial encoder: 3 dispatches for all 12 timesteps ----
  k_spl1T<<<gW, 256, 0, stream>>>(rp, ev, posj, x, gcn_w1, gcn_b1, h1b12);
  k_fusedT<64><<<dim3(gF, 12), 256, 0, stream>>>(ed, tstartp, rowoffp,
                                                 h1b12, w2f, gcn_b2, t1b12);
  k_fusedT<128><<<dim3(gF, 12), 256, 0, stream>>>(ed, tstartp, rowoffp,
                                                  t1b12, w3f, gcn_b3, hseqb);

  // ---- temporal attention ----
  k_att<<<(T_ * BNS_ + 63) / 64, 256, 0, stream>>>(hseqb, aw1f, att_b1, T_ * BNS_,
                                                   att_w2, att_b2, scores);
  k_attw<<<(BNS_ * 64 + 255) / 256, 256, 0, stream>>>(scores, hseqb, nfbf);

  // ---- GRU ----
  k_gruf<<<BNS_ / 64, 256, 0, stream>>>(nfbf, wihf, gru_bih, gru_bhh, ord,
                                        hst, hbf, out_w, out_b, out);

  // ---- graph ODE, RK4: 2 fused dispatches per f-eval ----
  const float dt = (float)FH_ / (float)(FH_ - 1);
  unsigned short* t1 = t1b12;  // reuse first BNS*128 of spatial scratch
  auto f_eval = [&](const unsigned short* inbf, int mode, float c1, float c2, int step) {
    k_fused<<<gF, 256, 0, stream>>>(ed, tstartp, rowoffp, ord, inbf, ow1f, ode_b1,
                                    0, 0.f, 0.f, t1, nullptr, nullptr, nullptr, nullptr,
                                    nullptr, nullptr, nullptr, 0);
    k_fused<<<gF, 256, 0, stream>>>(ed, tstartp, rowoffp, ord, t1, ow2f, ode_b2,
                                    mode, c1, c2, nullptr, hbf, rkb, hst,
                                    (mode == 3) ? hbf : ubf,
                                    out_w, out_b, out, step);
  };
  for (int s = 1; s < FH_; s++) {
    f_eval(hbf, 1, 0.5f * dt, 0.f, s);
    f_eval(ubf, 2, 0.5f * dt, 0.f, s);
    f_eval(ubf, 2, dt, 0.f, s);
    f_eval(ubf, 3, 0.f, dt / 6.f, s);
  }
}

// Round 11
// 1735.841 us; speedup vs baseline: 1.3917x; 1.0186x over previous
//
#include <hip/hip_runtime.h>
#include <stdint.h>

#define B_ 4
#define N_ 5000
#define T_ 12
#define FH_ 12
#define H_ 128
#define BN_ 20000
#define E_ 320000
#define TOTE_ (E_ + BN_)
#define EVCAP_ (TOTE_ + BN_)   // CSR with even-alignment pads
#define EDCAP_ 190000          // packed per-tile edge PAIR capacity
#define NTB_ 313               // 16-row tiles per batch
#define NT_ 1252               // total tiles
#define SLOTB_ 5008            // slots per batch (NTB_*16)
#define BNS_ 20032             // total slots
#define DCAP_ 512              // per-tile pair descriptor LDS capacity

typedef __attribute__((ext_vector_type(8))) short s8v;
typedef __attribute__((ext_vector_type(4))) float f32x4;

__device__ __forceinline__ float fast_tanh(float x) {
  float e = __expf(2.f * x);
  return 1.f - 2.f * __builtin_amdgcn_rcpf(e + 1.f);
}
__device__ __forceinline__ float fast_sigmoid(float x) {
  return __builtin_amdgcn_rcpf(1.f + __expf(-x));
}
__device__ __forceinline__ unsigned short f2bf(float f) {  // RNE
  unsigned u = __float_as_uint(f);
  u = (u + 0x7fffu + ((u >> 16) & 1u)) >> 16;
  return (unsigned short)u;
}
__device__ __forceinline__ float bf2f(unsigned short u) {
  return __uint_as_float(((unsigned)u) << 16);
}
__device__ __forceinline__ unsigned pack2(float lo, float hi) {
  return ((unsigned)f2bf(hi) << 16) | f2bf(lo);
}
// acc += pA_col*wA + pB_col*wB   (pp = {pA_col, pB_col} bf16x2, wp = {wA, wB})
#define DOT2ACC(accv, pa, pb, sel)                                         \
  {                                                                        \
    unsigned pp_ = __builtin_amdgcn_perm((pb), (pa), (sel));               \
    asm("v_dot2_f32_bf16 %0, %1, %2, %0" : "+v"(accv) : "v"(pp_), "v"(wp)); \
  }

__global__ void k_sentinel(float* out) { out[0] = 1e30f; }

__global__ void k_init_cnt(int* cnt) {
  int i = blockIdx.x * 256 + threadIdx.x;
  if (i < BN_) cnt[i] = 1;  // self-loop
}
__global__ void k_count(const int* __restrict__ dst, int* cnt) {
  int e = blockIdx.x * 256 + threadIdx.x;
  if (e < E_) atomicAdd(&cnt[dst[e]], 1);
}
// exclusive scan of cnt -> rp (row starts EVEN-aligned), dinv=rsqrt(cnt); zero cnt
__global__ void k_scan(int* cnt, int* rp, float* dinv) {
  __shared__ int sh[1024];
  int tid = threadIdx.x;
  const int per = (BN_ + 1023) / 1024;
  int start = tid * per;
  int end = start + per; if (end > BN_) end = BN_;
  int s = 0;
  for (int i = start; i < end; i++) {
    int c = cnt[i];
    dinv[i] = rsqrtf((float)c);
    s += (c + 1) & ~1;
  }
  sh[tid] = s;
  __syncthreads();
  for (int off = 1; off < 1024; off <<= 1) {
    int v = (tid >= off) ? sh[tid - off] : 0;
    __syncthreads();
    sh[tid] += v;
    __syncthreads();
  }
  int run = (tid > 0) ? sh[tid - 1] : 0;
  for (int i = start; i < end; i++) {
    int c = cnt[i];
    rp[i] = run;
    run += (c + 1) & ~1;
    cnt[i] = 0;
  }
  if (tid == 1023) rp[BN_] = sh[1023];
}
// ev[pos] = {src*128, bits(dinv[s]*dinv[d])}; pad slots stay zero (memset)
__global__ void k_fill(const int* __restrict__ src, const int* __restrict__ dst,
                       const int* __restrict__ rp, int* cnt, int2* ev,
                       const float* __restrict__ dinv) {
  int e = blockIdx.x * 256 + threadIdx.x;
  if (e >= TOTE_) return;
  int s, d;
  if (e < E_) { s = src[e]; d = dst[e]; }
  else { s = d = e - E_; }
  int pos = rp[d] + atomicAdd(&cnt[d], 1);
  int2 p; p.x = s * 128; p.y = __float_as_int(dinv[s] * dinv[d]);
  ev[pos] = p;
}

// ---- degree sort (per batch, DESCENDING) + inverse permutation ----
__global__ void k_hist(const int* __restrict__ rp, int* hist) {
  int i = blockIdx.x * 256 + threadIdx.x;
  if (i < BN_) {
    int d = (rp[i + 1] - rp[i]) >> 1; d = d > 63 ? 63 : d;
    atomicAdd(&hist[(i / N_) * 64 + (63 - d)], 1);
  }
}
__global__ void k_binscan(int* hist) {
  __shared__ int sh[256];
  int t = threadIdx.x;
  int val = hist[t];
  sh[t] = val;
  __syncthreads();
  for (int o = 1; o < 256; o <<= 1) {
    int v = (t >= o) ? sh[t - o] : 0;
    __syncthreads();
    sh[t] += v;
    __syncthreads();
  }
  hist[t] = sh[t] - val;
}
__global__ void k_scatter(const int* __restrict__ rp, int* hist, int* ord, int* posj) {
  int i = blockIdx.x * 256 + threadIdx.x;
  if (i < BN_) {
    int d = (rp[i + 1] - rp[i]) >> 1; d = d > 63 ? 63 : d;
    int gpos = atomicAdd(&hist[(i / N_) * 64 + (63 - d)], 1);
    ord[gpos] = i;
    posj[i] = gpos - (i / N_) * N_;  // within-batch sorted index
  }
}

// per-tile row pair-offsets + tile pair counts
__global__ void k_rowoff(const int* __restrict__ rp, const int* __restrict__ ord,
                         int* rowoffp, int* tcntp) {
  int t = blockIdx.x * 256 + threadIdx.x;
  if (t >= NT_) return;
  int bb = t / NTB_, within = t % NTB_;
  int acc = 0;
  for (int r = 0; r < 16; r++) {
    int j = within * 16 + r;
    int plen = 0;
    if (j < N_) {
      int row = ord[bb * N_ + j];
      plen = (rp[row + 1] - rp[row]) >> 1;
    }
    rowoffp[t * 16 + r] = acc;
    acc += plen;
  }
  tcntp[t] = acc;
}
__global__ void k_tscan(const int* __restrict__ tcnt, int* __restrict__ tstart) {
  __shared__ int sh[1024];
  int tid = threadIdx.x;
  int st = tid * 2, en = st + 2; if (en > NT_) en = NT_;
  int s = 0;
  for (int i = st; i < en; i++) s += tcnt[i];
  sh[tid] = s;
  __syncthreads();
  for (int o = 1; o < 1024; o <<= 1) {
    int v = (tid >= o) ? sh[tid - o] : 0;
    __syncthreads();
    sh[tid] += v;
    __syncthreads();
  }
  int run = tid ? sh[tid - 1] : 0;
  for (int i = st; i < en; i++) { tstart[i] = run; run += tcnt[i]; }
  if (tid == 1023) tstart[NT_] = sh[1023];
}
// packed per-tile pair descriptors: {slotA | slotB<<16, {wA,wB} bf16x2}
__global__ void k_edfill(const int* __restrict__ rp, const int* __restrict__ ord,
                         const int* __restrict__ posj, const int2* __restrict__ ev,
                         const int* __restrict__ tstartp, const int* __restrict__ rowoffp,
                         int2* __restrict__ ed) {
  int idx = blockIdx.x * 256 + threadIdx.x;
  if (idx >= NT_ * 16) return;
  int t = idx >> 4, r = idx & 15;
  int bb = t / NTB_, within = t % NTB_;
  int j = within * 16 + r;
  if (j >= N_) return;
  int row = ord[bb * N_ + j];
  int b0 = rp[row], len = rp[row + 1] - b0;  // padded even
  int dst = tstartp[t] + rowoffp[t * 16 + r];
  for (int i = 0; i < len; i += 2) {
    int2 pA = ev[b0 + i], pB = ev[b0 + i + 1];
    int sA = pA.x >> 7, sB = pB.x >> 7;
    int slotA = (sA / N_) * SLOTB_ + posj[sA];
    int slotB = (sB / N_) * SLOTB_ + posj[sB];
    unsigned wp = ((unsigned)f2bf(__int_as_float(pB.y)) << 16) |
                  f2bf(__int_as_float(pA.y));
    int2 o; o.x = slotA | (slotB << 16); o.y = (int)wp;
    ed[dst + (i >> 1)] = o;
  }
}

// MFMA B-frag pack
__device__ __forceinline__ void prep_one(const float* __restrict__ src,
                                         unsigned short* __restrict__ dst,
                                         int K, int Nn, int transposed, int idx) {
  int j = idx & 7, l = (idx >> 3) & 63, rest = idx >> 9;
  int NT = Nn >> 4;
  int nt = rest % NT, kc = rest / NT;
  int k = kc * 32 + ((l >> 4) << 3) + j;
  int n = nt * 16 + (l & 15);
  float v = transposed ? src[n * K + k] : src[k * Nn + n];
  dst[idx] = f2bf(v);
}
__global__ void k_prep_all(const float* w2, const float* w3, const float* a1,
                           const float* o1, const float* o2, const float* wih,
                           unsigned short* w2f, unsigned short* w3f, unsigned short* a1f,
                           unsigned short* o1f, unsigned short* o2f, unsigned short* wihf) {
  int idx = blockIdx.x * 256 + threadIdx.x;
  if (idx < 8192) { prep_one(w2, w2f, 64, 128, 0, idx); return; }
  idx -= 8192;
  if (idx < 16384) { prep_one(w3, w3f, 128, 128, 0, idx); return; }
  idx -= 16384;
  if (idx < 16384) { prep_one(a1, a1f, 128, 128, 0, idx); return; }
  idx -= 16384;
  if (idx < 16384) { prep_one(o1, o1f, 128, 128, 0, idx); return; }
  idx -= 16384;
  if (idx < 16384) { prep_one(o2, o2f, 128, 128, 0, idx); return; }
  idx -= 16384;
  if (idx < 49152) prep_one(wih, wihf, 128, 384, 1, idx);
}

// all-T layer1; stores into slot order
__global__ void k_spl1T(const int* __restrict__ rp, const int2* __restrict__ ev,
                        const int* __restrict__ posj,
                        const float* __restrict__ x,
                        const float* __restrict__ w1, const float* __restrict__ b1,
                        unsigned short* __restrict__ h1) {
  int wid = (blockIdx.x * 256 + threadIdx.x) >> 6;
  int lane = threadIdx.x & 63;
  if (wid >= BN_) return;
  int beg = rp[wid], end = rp[wid + 1];
  float a[12];
#pragma unroll
  for (int t = 0; t < 12; t++) a[t] = 0.f;
  for (int e = beg + lane; e < end; e += 64) {
    int2 p = ev[e];
    const float4* xp = (const float4*)(x + (size_t)(p.x >> 7) * 12);
    float v = __int_as_float(p.y);
    float4 x0 = xp[0], x1 = xp[1], x2 = xp[2];
    a[0] = fmaf(v, x0.x, a[0]);  a[1] = fmaf(v, x0.y, a[1]);
    a[2] = fmaf(v, x0.z, a[2]);  a[3] = fmaf(v, x0.w, a[3]);
    a[4] = fmaf(v, x1.x, a[4]);  a[5] = fmaf(v, x1.y, a[5]);
    a[6] = fmaf(v, x1.z, a[6]);  a[7] = fmaf(v, x1.w, a[7]);
    a[8] = fmaf(v, x2.x, a[8]);  a[9] = fmaf(v, x2.y, a[9]);
    a[10] = fmaf(v, x2.z, a[10]); a[11] = fmaf(v, x2.w, a[11]);
  }
#pragma unroll
  for (int t = 0; t < 12; t++)
#pragma unroll
    for (int m = 1; m < 64; m <<= 1) a[t] += __shfl_xor(a[t], m);
  float wv = w1[lane], bv = b1[lane];
  int slot = (wid / N_) * SLOTB_ + posj[wid];
#pragma unroll
  for (int t = 0; t < 12; t++) {
    float v = fmaf(a[t], wv, bv);
    h1[((size_t)t * BNS_ + slot) * 64 + lane] = f2bf(fmaxf(v, 0.f));
  }
}

// ---- LDS-descriptor 4-way edge-split gather, v_perm + v_dot2_f32_bf16 core ----
template<int KIN>
__device__ __forceinline__ void gather_tile(
    const int2* __restrict__ ed, const int* __restrict__ tstartp,
    const int* __restrict__ rowoffp, const unsigned short* __restrict__ in,
    unsigned short (*agg)[KIN + 8], int2* desc, int tileid, int w, int l, int tid) {
  constexpr int SH = (KIN == 128) ? 7 : 6;
  constexpr int CW = KIN / 16;
  const int h = l >> 4, c = l & 15;
  const unsigned short* inc = in + c * CW;
  int tp0 = tstartp[tileid];
  int npair = tstartp[tileid + 1] - tp0;
  if (npair > DCAP_) npair = DCAP_;   // capacity guard (never hit for this graph)
  const int2* edp = ed + tp0;
  for (int i = tid; i < npair; i += 256) desc[i] = edp[i];
  __syncthreads();
  int q0[4], qlen[4];
  float a[4][CW];
  int mx = 0;
  const int* rot = rowoffp + tileid * 16;
#pragma unroll
  for (int r = 0; r < 4; r++) {
    int lr = w * 4 + r;
    int ro = rot[lr];
    int rn = (lr == 15) ? npair : rot[lr + 1];
    int lenp = rn - ro;
    int s0 = (lenp * h) >> 2, s1 = (lenp * (h + 1)) >> 2;
    q0[r] = ro + s0;
    qlen[r] = s1 - s0;
    mx = qlen[r] > mx ? qlen[r] : mx;
#pragma unroll
    for (int q = 0; q < CW; q++) a[r][q] = 0.f;
  }
  int lim = npair - 1;
  for (int i = 0; i < mx; i++) {
#pragma unroll
    for (int r = 0; r < 4; r++) {
      int idx = q0[r] + i; idx = idx > lim ? lim : idx;
      int2 d = desc[idx];                 // unguarded LDS read (pipelinable)
      if (i < qlen[r]) {
        unsigned sa = (unsigned)d.x & 0xffffu;
        unsigned sb = (unsigned)d.x >> 16;
        unsigned wp = (unsigned)d.y;
        if (KIN == 128) {
          uint4 PA = *(const uint4*)(inc + ((size_t)sa << SH));
          uint4 PB = *(const uint4*)(inc + ((size_t)sb << SH));
          DOT2ACC(a[r][0], PA.x, PB.x, 0x05040100u);
          DOT2ACC(a[r][1], PA.x, PB.x, 0x07060302u);
          DOT2ACC(a[r][2], PA.y, PB.y, 0x05040100u);
          DOT2ACC(a[r][3], PA.y, PB.y, 0x07060302u);
          DOT2ACC(a[r][4], PA.z, PB.z, 0x05040100u);
          DOT2ACC(a[r][5], PA.z, PB.z, 0x07060302u);
          DOT2ACC(a[r][6], PA.w, PB.w, 0x05040100u);
          DOT2ACC(a[r][7], PA.w, PB.w, 0x07060302u);
        } else {
          uint2 PA = *(const uint2*)(inc + ((size_t)sa << SH));
          uint2 PB = *(const uint2*)(inc + ((size_t)sb << SH));
          DOT2ACC(a[r][0], PA.x, PB.x, 0x05040100u);
          DOT2ACC(a[r][1], PA.x, PB.x, 0x07060302u);
          DOT2ACC(a[r][2], PA.y, PB.y, 0x05040100u);
          DOT2ACC(a[r][3], PA.y, PB.y, 0x07060302u);
        }
      }
    }
  }
#pragma unroll
  for (int r = 0; r < 4; r++) {
#pragma unroll
    for (int q2 = 0; q2 < CW; q2++) {
      a[r][q2] += __shfl_xor(a[r][q2], 16);
      a[r][q2] += __shfl_xor(a[r][q2], 32);
    }
    if (h == 0) {
      if (KIN == 128) {
        uint4 o;
        o.x = pack2(a[r][0], a[r][1]); o.y = pack2(a[r][2], a[r][3]);
        o.z = pack2(a[r][4], a[r][5]); o.w = pack2(a[r][6], a[r][7]);
        *(uint4*)&agg[w * 4 + r][c * 8] = o;
      } else {
        uint2 o;
        o.x = pack2(a[r][0], a[r][1]); o.y = pack2(a[r][2], a[r][3]);
        *(uint2*)&agg[w * 4 + r][c * 4] = o;
      }
    }
  }
}

template<int KIN>
__device__ __forceinline__ void mfma_tile(
    const unsigned short (*agg)[KIN + 8], const unsigned short* __restrict__ Wf,
    int w, int l, f32x4 acc[2]) {
  constexpr int KC = KIN / 32;
  const int hi = l >> 4, lo16 = l & 15;
  acc[0] = (f32x4){0.f, 0.f, 0.f, 0.f};
  acc[1] = (f32x4){0.f, 0.f, 0.f, 0.f};
#pragma unroll
  for (int kc = 0; kc < KC; kc++) {
    s8v av = *(const s8v*)&agg[lo16][kc * 32 + hi * 8];
#pragma unroll
    for (int q = 0; q < 2; q++) {
      s8v bv = *(const s8v*)(Wf + (((size_t)(kc * 8 + 2 * w + q)) << 9) + (l << 3));
      acc[q] = __builtin_amdgcn_mfma_f32_16x16x32_bf16(av, bv, acc[q], 0, 0, 0);
    }
  }
}

// spatial fused SpMM+GEMM (relu), batched over t = blockIdx.y; slot-linear I/O
template<int KIN>
__global__ __launch_bounds__(256) void k_fusedT(
    const int2* __restrict__ ed, const int* __restrict__ tstartp,
    const int* __restrict__ rowoffp,
    const unsigned short* __restrict__ inb, const unsigned short* __restrict__ Wf,
    const float* __restrict__ bias, unsigned short* __restrict__ outb) {
  __shared__ __align__(16) int2 desc[DCAP_];
  __shared__ unsigned short agg[16][KIN + 8];
  const int tid = threadIdx.x, l = tid & 63, w = tid >> 6;
  const int t = blockIdx.y;
  const unsigned short* in = inb + (size_t)t * BNS_ * KIN;
  unsigned short* out = outb + (size_t)t * BNS_ * 128;
  const int bid = blockIdx.x;
  const int xcd = bid & 7, slot = bid >> 3;
  const int bb = xcd >> 1;
  const int within = slot * 2 + (xcd & 1);
  if (within >= NTB_) return;
  int nv = N_ - within * 16; nv = nv > 16 ? 16 : nv;
  const int tileid = bb * NTB_ + within;
  gather_tile<KIN>(ed, tstartp, rowoffp, in, agg, desc, tileid, w, l, tid);
  __syncthreads();
  f32x4 acc[2];
  mfma_tile<KIN>(agg, Wf, w, l, acc);
  const int hi = l >> 4, lo16 = l & 15;
  const int rowbase = tileid * 16;
#pragma unroll
  for (int q = 0; q < 2; q++) {
    int col = (2 * w + q) * 16 + lo16;
    float bi = bias[col];
#pragma unroll
    for (int reg = 0; reg < 4; reg++) {
      int lr = hi * 4 + reg;
      if (lr < nv)
        out[(size_t)(rowbase + lr) * 128 + col] = f2bf(fmaxf(acc[q][reg] + bi, 0.f));
    }
  }
}

// ODE fused SpMM+GEMM+epilogue (KIN=128), slot-linear state tensors
__global__ __launch_bounds__(256) void k_fused(
    const int2* __restrict__ ed, const int* __restrict__ tstartp,
    const int* __restrict__ rowoffp, const int* __restrict__ ord,
    const unsigned short* __restrict__ in,
    const unsigned short* __restrict__ Wf, const float* __restrict__ bias,
    int mode, float c1, float c2,
    unsigned short* __restrict__ outb,
    const unsigned short* __restrict__ hbfin, unsigned short* __restrict__ rkb,
    float* __restrict__ h, unsigned short* __restrict__ ubfout,
    const float* __restrict__ ow, const float* __restrict__ ob,
    float* __restrict__ outp, int step) {
  __shared__ __align__(16) int2 desc[DCAP_];
  __shared__ unsigned short agg[16][136];
  __shared__ float ppart[4][16];
  const int tid = threadIdx.x, l = tid & 63, w = tid >> 6;
  const int bid = blockIdx.x;
  const int xcd = bid & 7, slot = bid >> 3;
  const int bb = xcd >> 1;
  const int within = slot * 2 + (xcd & 1);
  if (within >= NTB_) return;
  int nv = N_ - within * 16; nv = nv > 16 ? 16 : nv;
  const int tileid = bb * NTB_ + within;
  gather_tile<128>(ed, tstartp, rowoffp, in, agg, desc, tileid, w, l, tid);
  __syncthreads();
  f32x4 acc[2];
  mfma_tile<128>(agg, Wf, w, l, acc);
  const int hi = l >> 4, lo16 = l & 15;
  const int rowbase = tileid * 16;
  float p[4] = {0.f, 0.f, 0.f, 0.f};
#pragma unroll
  for (int q = 0; q < 2; q++) {
    int col = (2 * w + q) * 16 + lo16;
    float bi = bias[col];
    float owv = (mode == 3) ? ow[col] : 0.f;
#pragma unroll
    for (int reg = 0; reg < 4; reg++) {
      int lr = hi * 4 + reg;
      if (lr >= nv) continue;
      size_t oi = (size_t)(rowbase + lr) * 128 + col;
      float v = fast_tanh(acc[q][reg] + bi);
      if (mode == 0) {
        outb[oi] = f2bf(v);
      } else if (mode == 1) {
        rkb[oi] = f2bf(v);
        ubfout[oi] = f2bf(fmaf(c1, v, bf2f(hbfin[oi])));
      } else if (mode == 2) {
        rkb[oi] = f2bf(bf2f(rkb[oi]) + 2.f * v);
        ubfout[oi] = f2bf(fmaf(c1, v, bf2f(hbfin[oi])));
      } else {
        float nh = fmaf(c2, bf2f(rkb[oi]) + v, h[oi]);
        h[oi] = nh;
        ubfout[oi] = f2bf(nh);
        p[reg] = fmaf(nh, owv, p[reg]);
      }
    }
  }
  if (mode == 3) {
#pragma unroll
    for (int m = 1; m <= 8; m <<= 1)
#pragma unroll
      for (int reg = 0; reg < 4; reg++) p[reg] += __shfl_xor(p[reg], m);
    if (lo16 == 0)
#pragma unroll
      for (int reg = 0; reg < 4; reg++) ppart[w][hi * 4 + reg] = p[reg];
    __syncthreads();
    if (tid < 16 && tid < nv) {
      int orig = ord[bb * N_ + within * 16 + tid];
      outp[(size_t)orig * FH_ + step] =
          ppart[0][tid] + ppart[1][tid] + ppart[2][tid] + ppart[3][tid] + ob[0];
    }
  }
}

// attention scores (rows = 12*BNS_ slots)
__global__ __launch_bounds__(256) void k_att(
    const unsigned short* __restrict__ A, const unsigned short* __restrict__ Wf,
    const float* __restrict__ bias, int nrows,
    const float* __restrict__ w2v, const float* __restrict__ b2,
    float* __restrict__ scores) {
  const int tid = threadIdx.x;
  const int l = tid & 63;
  const int w = tid >> 6;
  const int m0 = blockIdx.x * 64 + w * 16;

  f32x4 acc[8];
#pragma unroll
  for (int nt = 0; nt < 8; nt++) acc[nt] = (f32x4){0.f, 0.f, 0.f, 0.f};
  int arow = m0 + (l & 15);
  if (arow >= nrows) arow = nrows - 1;
  const unsigned short* Ap = A + (size_t)arow * 128 + ((l >> 4) << 3);
#pragma unroll
  for (int kc = 0; kc < 4; kc++) {
    s8v av = *(const s8v*)(Ap + kc * 32);
#pragma unroll
    for (int nt = 0; nt < 8; nt++) {
      s8v bv = *(const s8v*)(Wf + (((size_t)(kc * 8 + nt)) << 9) + (l << 3));
      acc[nt] = __builtin_amdgcn_mfma_f32_16x16x32_bf16(av, bv, acc[nt], 0, 0, 0);
    }
  }
  float p[4] = {0.f, 0.f, 0.f, 0.f};
#pragma unroll
  for (int nt = 0; nt < 8; nt++) {
    int col = nt * 16 + (l & 15);
    float bi = bias[col], wv = w2v[col];
#pragma unroll
    for (int reg = 0; reg < 4; reg++)
      p[reg] = fmaf(fast_tanh(acc[nt][reg] + bi), wv, p[reg]);
  }
#pragma unroll
  for (int m = 1; m <= 8; m <<= 1)
#pragma unroll
    for (int reg = 0; reg < 4; reg++) p[reg] += __shfl_xor(p[reg], m);
  if ((l & 15) == 0) {
    float bb = b2[0];
#pragma unroll
    for (int reg = 0; reg < 4; reg++) {
      int row = m0 + ((l >> 4) << 2) + reg;
      if (row < nrows) scores[row] = p[reg] + bb;
    }
  }
}

// fused softmax + weighted sum over slots
__global__ void k_attw(const float* __restrict__ sc, const unsigned short* __restrict__ hs,
                       unsigned short* __restrict__ nf) {
  int idx = blockIdx.x * 256 + threadIdx.x;
  if (idx >= BNS_ * 64) return;
  int bn = idx >> 6, c = idx & 63;
  float v[T_];
  float m = -1e30f;
#pragma unroll
  for (int t = 0; t < T_; t++) { v[t] = sc[t * BNS_ + bn]; m = fmaxf(m, v[t]); }
  float ssum = 0.f;
#pragma unroll
  for (int t = 0; t < T_; t++) { v[t] = __expf(v[t] - m); ssum += v[t]; }
  float inv = __builtin_amdgcn_rcpf(ssum);
  float s0 = 0.f, s1 = 0.f;
#pragma unroll
  for (int t = 0; t < T_; t++) {
    unsigned p = *(const unsigned*)(hs + ((size_t)t * BNS_ + bn) * 128 + c * 2);
    float aw = v[t] * inv;
    s0 = fmaf(aw, bf2f((unsigned short)(p & 0xffffu)), s0);
    s1 = fmaf(aw, bf2f((unsigned short)(p >> 16)), s1);
  }
  *(unsigned*)(nf + (size_t)bn * 128 + c * 2) = pack2(s0, s1);
}

// fused GRU + step-0 projection (slot-order; un-permute via ord for outp)
__global__ __launch_bounds__(256) void k_gruf(
    const unsigned short* __restrict__ A, const unsigned short* __restrict__ Wf,
    const float* __restrict__ bih, const float* __restrict__ bhh,
    const int* __restrict__ ord,
    float* __restrict__ hst, unsigned short* __restrict__ hbf,
    const float* __restrict__ ow, const float* __restrict__ ob,
    float* __restrict__ outp) {
  const int tid = threadIdx.x;
  const int l = tid & 63;
  const int w = tid >> 6;
  const int m0 = blockIdx.x * 64 + w * 16;

  f32x4 acc[24];
#pragma unroll
  for (int nt = 0; nt < 24; nt++) acc[nt] = (f32x4){0.f, 0.f, 0.f, 0.f};
  int arow = m0 + (l & 15);
  const unsigned short* Ap = A + (size_t)arow * 128 + ((l >> 4) << 3);
#pragma unroll
  for (int kc = 0; kc < 4; kc++) {
    s8v av = *(const s8v*)(Ap + kc * 32);
#pragma unroll
    for (int nt = 0; nt < 24; nt++) {
      s8v bv = *(const s8v*)(Wf + (((size_t)(kc * 24 + nt)) << 9) + (l << 3));
      acc[nt] = __builtin_amdgcn_mfma_f32_16x16x32_bf16(av, bv, acc[nt], 0, 0, 0);
    }
  }
  const int hi = l >> 4, lo16 = l & 15;
  float p[4] = {0.f, 0.f, 0.f, 0.f};
#pragma unroll
  for (int nt = 0; nt < 8; nt++) {
    int col = nt * 16 + lo16;
    float br = bih[col], bz = bih[col + 128], bn = bih[col + 256];
    float hr = bhh[col], hz = bhh[col + 128], hn = bhh[col + 256];
    float owv = ow[col];
#pragma unroll
    for (int reg = 0; reg < 4; reg++) {
      int slot = m0 + hi * 4 + reg;
      float r = fast_sigmoid(acc[nt][reg] + br + hr);
      float z = fast_sigmoid(acc[nt + 8][reg] + bz + hz);
      float n = fast_tanh(acc[nt + 16][reg] + bn + r * hn);
      float hv = (1.f - z) * n;  // h0 = 0
      size_t oi = (size_t)slot * 128 + col;
      hst[oi] = hv;
      hbf[oi] = f2bf(hv);
      p[reg] = fmaf(hv, owv, p[reg]);
    }
  }
#pragma unroll
  for (int m = 1; m <= 8; m <<= 1)
#pragma unroll
    for (int reg = 0; reg < 4; reg++) p[reg] += __shfl_xor(p[reg], m);
  if (lo16 == 0) {
    float obv = ob[0];
#pragma unroll
    for (int reg = 0; reg < 4; reg++) {
      int slot = m0 + hi * 4 + reg;
      int bbv = slot / SLOTB_;
      int j = slot - bbv * SLOTB_;
      if (j < N_) {
        int orig = ord[bbv * N_ + j];
        outp[(size_t)orig * FH_ + 0] = p[reg] + obv;
      }
    }
  }
}

extern "C" void kernel_launch(void* const* d_in, const int* in_sizes, int n_in,
                              void* d_out, int out_size, void* d_ws, size_t ws_size,
                              hipStream_t stream) {
  const float* x       = (const float*)d_in[0];
  const float* gcn_w1  = (const float*)d_in[1];
  const float* gcn_b1  = (const float*)d_in[2];
  const float* gcn_w2  = (const float*)d_in[3];
  const float* gcn_b2  = (const float*)d_in[4];
  const float* gcn_w3  = (const float*)d_in[5];
  const float* gcn_b3  = (const float*)d_in[6];
  const float* att_w1  = (const float*)d_in[7];
  const float* att_b1  = (const float*)d_in[8];
  const float* att_w2  = (const float*)d_in[9];
  const float* att_b2  = (const float*)d_in[10];
  const float* gru_wih = (const float*)d_in[11];
  const float* gru_bih = (const float*)d_in[13];
  const float* gru_bhh = (const float*)d_in[14];
  const float* ode_w1  = (const float*)d_in[15];
  const float* ode_b1  = (const float*)d_in[16];
  const float* ode_w2  = (const float*)d_in[17];
  const float* ode_b2  = (const float*)d_in[18];
  const float* out_w   = (const float*)d_in[19];
  const float* out_b   = (const float*)d_in[20];
  const int*   eidx    = (const int*)d_in[21];
  float* out = (float*)d_out;

  float* wsf = (float*)d_ws;
  size_t off = 0;
  unsigned short* h1b12 = (unsigned short*)(wsf + off); off += (size_t)12 * BNS_ * 32;
  float* hst    = wsf + off; off += (size_t)BNS_ * H_;
  float* scores = wsf + off; off += (size_t)T_ * BNS_;
  float* dinv   = wsf + off; off += BN_;
  int2*  ev     = (int2*)(wsf + off); off += (size_t)EVCAP_ * 2;   // 16B-aligned
  int2*  ed     = (int2*)(wsf + off); off += (size_t)EDCAP_ * 2;   // pair descriptors
  unsigned short* hseqb  = (unsigned short*)(wsf + off); off += (size_t)T_ * BNS_ * 64;
  unsigned short* t1b12  = (unsigned short*)(wsf + off); off += (size_t)T_ * BNS_ * 64;
  unsigned short* hbf    = (unsigned short*)(wsf + off); off += (size_t)BNS_ * 64;
  unsigned short* ubf    = (unsigned short*)(wsf + off); off += (size_t)BNS_ * 64;
  unsigned short* rkb    = (unsigned short*)(wsf + off); off += (size_t)BNS_ * 64;
  unsigned short* nfbf   = (unsigned short*)(wsf + off); off += (size_t)BNS_ * 64;
  unsigned short* w2f    = (unsigned short*)(wsf + off); off += 64 * 128 / 2;
  unsigned short* w3f    = (unsigned short*)(wsf + off); off += 128 * 128 / 2;
  unsigned short* aw1f   = (unsigned short*)(wsf + off); off += 128 * 128 / 2;
  unsigned short* ow1f   = (unsigned short*)(wsf + off); off += 128 * 128 / 2;
  unsigned short* ow2f   = (unsigned short*)(wsf + off); off += 128 * 128 / 2;
  unsigned short* wihf   = (unsigned short*)(wsf + off); off += 128 * 384 / 2;
  int* rp      = (int*)(wsf + off); off += BN_ + 1;
  int* cnt     = (int*)(wsf + off); off += BN_;
  int* ord     = (int*)(wsf + off); off += BN_;
  int* posj    = (int*)(wsf + off); off += BN_;
  int* hist    = (int*)(wsf + off); off += 256;
  int* rowoffp = (int*)(wsf + off); off += (size_t)NT_ * 16;
  int* tcntp   = (int*)(wsf + off); off += NT_;
  int* tstartp = (int*)(wsf + off); off += NT_ + 1;
  if (ws_size < off * sizeof(float)) {
    k_sentinel<<<1, 1, 0, stream>>>(out);
    return;
  }

  const int* esrc = eidx;
  const int* edst = eidx + E_;
  const int g79 = (BN_ + 255) / 256;

  // ---- CSR + degree sort + packed pair descriptors + weight prep ----
  hipMemsetAsync(ev, 0, (size_t)EVCAP_ * sizeof(int2), stream);
  hipMemsetAsync(hist, 0, 256 * sizeof(int), stream);
  k_init_cnt<<<g79, 256, 0, stream>>>(cnt);
  k_count<<<(E_ + 255) / 256, 256, 0, stream>>>(edst, cnt);
  k_scan<<<1, 1024, 0, stream>>>(cnt, rp, dinv);
  k_fill<<<(TOTE_ + 255) / 256, 256, 0, stream>>>(esrc, edst, rp, cnt, ev, dinv);
  k_hist<<<g79, 256, 0, stream>>>(rp, hist);
  k_binscan<<<1, 256, 0, stream>>>(hist);
  k_scatter<<<g79, 256, 0, stream>>>(rp, hist, ord, posj);
  k_rowoff<<<(NT_ + 255) / 256, 256, 0, stream>>>(rp, ord, rowoffp, tcntp);
  k_tscan<<<1, 1024, 0, stream>>>(tcntp, tstartp);
  k_edfill<<<(NT_ * 16 + 255) / 256, 256, 0, stream>>>(rp, ord, posj, ev,
                                                       tstartp, rowoffp, ed);
  k_prep_all<<<480, 256, 0, stream>>>(gcn_w2, gcn_w3, att_w1, ode_w1, ode_w2, gru_wih,
                                      w2f, w3f, aw1f, ow1f, ow2f, wihf);

  const int gW = BN_ / 4;
  const int gF = 1280;

  // ---- spatial encoder: 3 dispatches for all 12 timesteps ----
  k_spl1T<<<gW, 256, 0, stream>>>(rp, ev, posj, x, gcn_w1, gcn_b1, h1b12);
  k_fusedT<64><<<dim3(gF, 12), 256, 0, stream>>>(ed, tstartp, rowoffp,
                                                 h1b12, w2f, gcn_b2, t1b12);
  k_fusedT<128><<<dim3(gF, 12), 256, 0, stream>>>(ed, tstartp, rowoffp,
                                                  t1b12, w3f, gcn_b3, hseqb);

  // ---- temporal attention ----
  k_att<<<(T_ * BNS_ + 63) / 64, 256, 0, stream>>>(hseqb, aw1f, att_b1, T_ * BNS_,
                                                   att_w2, att_b2, scores);
  k_attw<<<(BNS_ * 64 + 255) / 256, 256, 0, stream>>>(scores, hseqb, nfbf);

  // ---- GRU ----
  k_gruf<<<BNS_ / 64, 256, 0, stream>>>(nfbf, wihf, gru_bih, gru_bhh, ord,
                                        hst, hbf, out_w, out_b, out);

  // ---- graph ODE, RK4: 2 fused dispatches per f-eval ----
  const float dt = (float)FH_ / (float)(FH_ - 1);
  unsigned short* t1 = t1b12;  // reuse first BNS*128 of spatial scratch
  auto f_eval = [&](const unsigned short* inbf, int mode, float c1, float c2, int step) {
    k_fused<<<gF, 256, 0, stream>>>(ed, tstartp, rowoffp, ord, inbf, ow1f, ode_b1,
                                    0, 0.f, 0.f, t1, nullptr, nullptr, nullptr, nullptr,
                                    nullptr, nullptr, nullptr, 0);
    k_fused<<<gF, 256, 0, stream>>>(ed, tstartp, rowoffp, ord, t1, ow2f, ode_b2,
                                    mode, c1, c2, nullptr, hbf, rkb, hst,
                                    (mode == 3) ? hbf : ubf,
                                    out_w, out_b, out, step);
  };
  for (int s = 1; s < FH_; s++) {
    f_eval(hbf, 1, 0.5f * dt, 0.f, s);
    f_eval(ubf, 2, 0.5f * dt, 0.f, s);
    f_eval(ubf, 2, dt, 0.f, s);
    f_eval(ubf, 3, 0.f, dt / 6.f, s);
  }
}